// Round 1
// baseline (1573.026 us; speedup 1.0000x reference)
//
#include <hip/hip_runtime.h>
#include <math.h>

#define NB 4
#define NN 32768
#define MM 32768
#define KK 16
#define HID 64
#define DIM 32
#define ENK (NN*KK)              // 524288 elements per batch
#define CNT_PER_GROUP (16.0f*(float)NN*(float)KK)
#define NEG_HUGE (-3.4028234663852886e38f)

// ---- workspace float offsets ----
#define WS_STATS1 0      // [4][8]  : per (b): s[g0..3], sq[g0..3]
#define WS_STATS2 32     // [4][8]
#define WS_W1F    64     // [4][64][4] folded pre_w1 * gn1
#define WS_B1F    1088   // [4][64]
#define WS_WA1F   1344   // [4][64][32] folded attn_w1 * gn2
#define WS_BA1F   9536   // [4][64]
// total 9792 floats = 39168 bytes

__device__ __forceinline__ void reduce8_and_atomic(float v[8], float* dst) {
  #pragma unroll
  for (int i = 0; i < 8; ++i) {
    float x = v[i];
    x += __shfl_down(x, 32);
    x += __shfl_down(x, 16);
    x += __shfl_down(x, 8);
    x += __shfl_down(x, 4);
    x += __shfl_down(x, 2);
    x += __shfl_down(x, 1);
    v[i] = x;
  }
  __shared__ float red[4][8];
  const int lane = threadIdx.x & 63;
  const int wv = threadIdx.x >> 6;
  if (lane == 0) {
    #pragma unroll
    for (int i = 0; i < 8; ++i) red[wv][i] = v[i];
  }
  __syncthreads();
  if (threadIdx.x < 8) {
    float t = red[0][threadIdx.x] + red[1][threadIdx.x] +
              red[2][threadIdx.x] + red[3][threadIdx.x];
    atomicAdd(dst + threadIdx.x, t);
  }
}

// lp = [dir_x, dir_y, dir_z, dist]
__device__ __forceinline__ void compute_lp(const float* __restrict__ qb,
                                           const float* __restrict__ kb,
                                           int n, int idx,
                                           float& lp0, float& lp1, float& lp2, float& lp3) {
  float dx = kb[idx]        - qb[n];
  float dy = kb[MM + idx]   - qb[NN + n];
  float dz = kb[2*MM + idx] - qb[2*NN + n];
  float dist = sqrtf(fmaf(dx, dx, fmaf(dy, dy, dz*dz)));
  float inv = 1.0f / fmaxf(dist, 1e-12f);
  lp0 = dx * inv; lp1 = dy * inv; lp2 = dz * inv; lp3 = dist;
}

// ---------------- Pass 1: stats of x1 = W1 @ lp + b1, per (b, group) ----------------
__global__ __launch_bounds__(256) void k_stats1(
    const float* __restrict__ q_xyzs, const float* __restrict__ k_xyzs,
    const int* __restrict__ knn_idx,
    const float* __restrict__ w1, const float* __restrict__ b1,
    float* __restrict__ ws)
{
  const int b   = blockIdx.x >> 8;     // 256 blocks per batch
  const int blk = blockIdx.x & 255;
  const float* qb  = q_xyzs + b*3*NN;
  const float* kb  = k_xyzs + b*3*MM;
  const int* idxb  = knn_idx + b*ENK;
  const float4* w1v = (const float4*)w1;

  float sacc[4] = {0.f,0.f,0.f,0.f};
  float qacc[4] = {0.f,0.f,0.f,0.f};

  for (int it = 0; it < 8; ++it) {
    int el = (blk*8 + it)*256 + threadIdx.x;
    int n = el >> 4;
    int idx = idxb[el];
    float lp0, lp1, lp2, lp3;
    compute_lp(qb, kb, n, idx, lp0, lp1, lp2, lp3);
    #pragma unroll
    for (int g = 0; g < 4; ++g) {
      float sg = 0.f, qg = 0.f;
      #pragma unroll
      for (int oo = 0; oo < 16; ++oo) {
        int o = g*16 + oo;
        float4 w = w1v[o];
        float x = fmaf(w.x, lp0, fmaf(w.y, lp1, fmaf(w.z, lp2, fmaf(w.w, lp3, b1[o]))));
        sg += x; qg += x*x;
      }
      sacc[g] += sg; qacc[g] += qg;
    }
  }
  float v[8] = {sacc[0],sacc[1],sacc[2],sacc[3],qacc[0],qacc[1],qacc[2],qacc[3]};
  reduce8_and_atomic(v, ws + WS_STATS1 + b*8);
}

// ---------------- Fold GN1 into W1 (per batch) ----------------
__global__ __launch_bounds__(64) void k_fold1(
    const float* __restrict__ w1, const float* __restrict__ b1,
    const float* __restrict__ gw, const float* __restrict__ gb,
    float* __restrict__ ws)
{
  int b = blockIdx.x, o = threadIdx.x, g = o >> 4;
  const float* st = ws + WS_STATS1 + b*8;
  float mu  = st[g] / CNT_PER_GROUP;
  float var = st[4+g] / CNT_PER_GROUP - mu*mu;
  float sc  = rsqrtf(var + 1e-5f) * gw[o];
  float4 w = ((const float4*)w1)[o];
  ((float4*)(ws + WS_W1F))[b*64 + o] = make_float4(w.x*sc, w.y*sc, w.z*sc, w.w*sc);
  (ws + WS_B1F)[b*64 + o] = (b1[o] - mu)*sc + gb[o];
}

// ---------------- Pass 2: stats of a1 = Wa1 @ pe + ba1, per (b, group) ----------------
__global__ __launch_bounds__(256) void k_stats2(
    const float* __restrict__ q_xyzs, const float* __restrict__ k_xyzs,
    const int* __restrict__ knn_idx,
    const float* __restrict__ w2, const float* __restrict__ b2,
    const float* __restrict__ wa1, const float* __restrict__ ba1,
    const float* __restrict__ ws)
{
  const int b   = blockIdx.x >> 8;
  const int blk = blockIdx.x & 255;
  const float* qb  = q_xyzs + b*3*NN;
  const float* kb  = k_xyzs + b*3*MM;
  const int* idxb  = knn_idx + b*ENK;
  const float4* w1fv = (const float4*)(ws + WS_W1F) + b*64;
  const float*  b1fb = ws + WS_B1F + b*64;
  const float4* w2v  = (const float4*)w2;
  const float4* wa1v = (const float4*)wa1;

  float sacc[4] = {0.f,0.f,0.f,0.f};
  float qacc[4] = {0.f,0.f,0.f,0.f};

  for (int it = 0; it < 8; ++it) {
    int el = (blk*8 + it)*256 + threadIdx.x;
    int n = el >> 4;
    int idx = idxb[el];
    float lp0, lp1, lp2, lp3;
    compute_lp(qb, kb, n, idx, lp0, lp1, lp2, lp3);

    float h1[HID];
    #pragma unroll
    for (int o = 0; o < HID; ++o) {
      float4 w = w1fv[o];
      float x = fmaf(w.x, lp0, fmaf(w.y, lp1, fmaf(w.z, lp2, fmaf(w.w, lp3, b1fb[o]))));
      h1[o] = fmaxf(x, 0.f);
    }
    float pe[DIM];
    #pragma unroll
    for (int j = 0; j < DIM; ++j) {
      float acc = b2[j];
      #pragma unroll
      for (int o4 = 0; o4 < 16; ++o4) {
        float4 w = w2v[j*16 + o4];
        acc = fmaf(w.x, h1[4*o4+0], acc);
        acc = fmaf(w.y, h1[4*o4+1], acc);
        acc = fmaf(w.z, h1[4*o4+2], acc);
        acc = fmaf(w.w, h1[4*o4+3], acc);
      }
      pe[j] = acc;
    }
    #pragma unroll
    for (int g = 0; g < 4; ++g) {
      float sg = 0.f, qg = 0.f;
      #pragma unroll
      for (int oo = 0; oo < 16; ++oo) {
        int o = g*16 + oo;
        float acc = ba1[o];
        #pragma unroll
        for (int j4 = 0; j4 < 8; ++j4) {
          float4 w = wa1v[o*8 + j4];
          acc = fmaf(w.x, pe[4*j4+0], acc);
          acc = fmaf(w.y, pe[4*j4+1], acc);
          acc = fmaf(w.z, pe[4*j4+2], acc);
          acc = fmaf(w.w, pe[4*j4+3], acc);
        }
        sg += acc; qg += acc*acc;
      }
      sacc[g] += sg; qacc[g] += qg;
    }
  }
  float v[8] = {sacc[0],sacc[1],sacc[2],sacc[3],qacc[0],qacc[1],qacc[2],qacc[3]};
  reduce8_and_atomic(v, (float*)ws + WS_STATS2 + b*8);
}

// ---------------- Fold GN2 into Wa1 (per batch) ----------------
__global__ __launch_bounds__(64) void k_fold2(
    const float* __restrict__ wa1, const float* __restrict__ ba1,
    const float* __restrict__ gw2, const float* __restrict__ gb2,
    float* __restrict__ ws)
{
  int b = blockIdx.x, o = threadIdx.x, g = o >> 4;
  const float* st = ws + WS_STATS2 + b*8;
  float mu  = st[g] / CNT_PER_GROUP;
  float var = st[4+g] / CNT_PER_GROUP - mu*mu;
  float sc  = rsqrtf(var + 1e-5f) * gw2[o];
  float4* dst = (float4*)(ws + WS_WA1F) + (b*64 + o)*8;
  const float4* src = (const float4*)wa1 + o*8;
  #pragma unroll
  for (int j4 = 0; j4 < 8; ++j4) {
    float4 w = src[j4];
    dst[j4] = make_float4(w.x*sc, w.y*sc, w.z*sc, w.w*sc);
  }
  (ws + WS_BA1F)[b*64 + o] = (ba1[o] - mu)*sc + gb2[o];
}

// ---------------- Pass 3: full forward + masked softmax over K + weighted sum ----------------
__global__ __launch_bounds__(256) void k_final(
    const float* __restrict__ q_xyzs, const float* __restrict__ k_xyzs,
    const int* __restrict__ knn_idx, const int* __restrict__ mask,
    const float* __restrict__ w2, const float* __restrict__ b2,
    const float* __restrict__ wa2, const float* __restrict__ ba2,
    const float* __restrict__ ws, float* __restrict__ out)
{
  const int e = blockIdx.x*256 + threadIdx.x;   // (b, n, k) with k innermost
  const int b = e >> 19;                        // ENK = 2^19
  const int r = e & (ENK - 1);
  const int n = r >> 4;
  const int k = threadIdx.x & 15;

  const float* qb = q_xyzs + b*3*NN;
  const float* kb = k_xyzs + b*3*MM;
  int idx = knn_idx[e];
  float lp0, lp1, lp2, lp3;
  compute_lp(qb, kb, n, idx, lp0, lp1, lp2, lp3);

  const float4* w1fv = (const float4*)(ws + WS_W1F) + b*64;
  const float*  b1fb = ws + WS_B1F + b*64;
  float h1[HID];
  #pragma unroll
  for (int o = 0; o < HID; ++o) {
    float4 w = w1fv[o];
    float x = fmaf(w.x, lp0, fmaf(w.y, lp1, fmaf(w.z, lp2, fmaf(w.w, lp3, b1fb[o]))));
    h1[o] = fmaxf(x, 0.f);
  }
  float pe[DIM];
  const float4* w2v = (const float4*)w2;
  #pragma unroll
  for (int j = 0; j < DIM; ++j) {
    float acc = b2[j];
    #pragma unroll
    for (int o4 = 0; o4 < 16; ++o4) {
      float4 w = w2v[j*16 + o4];
      acc = fmaf(w.x, h1[4*o4+0], acc);
      acc = fmaf(w.y, h1[4*o4+1], acc);
      acc = fmaf(w.z, h1[4*o4+2], acc);
      acc = fmaf(w.w, h1[4*o4+3], acc);
    }
    pe[j] = acc;
  }
  float h2[HID];
  const float4* wa1fv = (const float4*)(ws + WS_WA1F) + b*64*8;
  const float*  ba1fb = ws + WS_BA1F + b*64;
  #pragma unroll
  for (int o = 0; o < HID; ++o) {
    float acc = ba1fb[o];
    #pragma unroll
    for (int j4 = 0; j4 < 8; ++j4) {
      float4 w = wa1fv[o*8 + j4];
      acc = fmaf(w.x, pe[4*j4+0], acc);
      acc = fmaf(w.y, pe[4*j4+1], acc);
      acc = fmaf(w.z, pe[4*j4+2], acc);
      acc = fmaf(w.w, pe[4*j4+3], acc);
    }
    h2[o] = fmaxf(acc, 0.f);
  }
  float lg[DIM];
  const float4* wa2v = (const float4*)wa2;
  #pragma unroll
  for (int j = 0; j < DIM; ++j) {
    float acc = ba2[j];
    #pragma unroll
    for (int o4 = 0; o4 < 16; ++o4) {
      float4 w = wa2v[j*16 + o4];
      acc = fmaf(w.x, h2[4*o4+0], acc);
      acc = fmaf(w.y, h2[4*o4+1], acc);
      acc = fmaf(w.z, h2[4*o4+2], acc);
      acc = fmaf(w.w, h2[4*o4+3], acc);
    }
    lg[j] = acc;
  }

  const bool valid = mask[e] != 0;
  float* outb = out + b*(DIM*NN);

  #pragma unroll
  for (int j = 0; j < DIM; ++j) {
    float v = valid ? lg[j] : NEG_HUGE;
    float m = v;
    m = fmaxf(m, __shfl_xor(m, 1));
    m = fmaxf(m, __shfl_xor(m, 2));
    m = fmaxf(m, __shfl_xor(m, 4));
    m = fmaxf(m, __shfl_xor(m, 8));
    float p = __expf(v - m);                 // all-masked row -> p=1 everywhere (uniform)
    float s = p;
    s += __shfl_xor(s, 1);
    s += __shfl_xor(s, 2);
    s += __shfl_xor(s, 4);
    s += __shfl_xor(s, 8);
    float c = pe[j] * p;
    c += __shfl_xor(c, 1);
    c += __shfl_xor(c, 2);
    c += __shfl_xor(c, 4);
    c += __shfl_xor(c, 8);
    if (k == 0) outb[j*NN + n] = c / s;
  }
}

extern "C" void kernel_launch(void* const* d_in, const int* in_sizes, int n_in,
                              void* d_out, int out_size, void* d_ws, size_t ws_size,
                              hipStream_t stream) {
  (void)in_sizes; (void)n_in; (void)out_size; (void)ws_size;
  const float* q_xyzs   = (const float*)d_in[0];
  const float* k_xyzs   = (const float*)d_in[1];
  const int*   knn_idx  = (const int*)d_in[2];
  const int*   mask     = (const int*)d_in[3];
  const float* pre_w1   = (const float*)d_in[4];
  const float* pre_b1   = (const float*)d_in[5];
  const float* pre_gn_w = (const float*)d_in[6];
  const float* pre_gn_b = (const float*)d_in[7];
  const float* pre_w2   = (const float*)d_in[8];
  const float* pre_b2   = (const float*)d_in[9];
  const float* attn_w1  = (const float*)d_in[10];
  const float* attn_b1  = (const float*)d_in[11];
  const float* attn_gn_w= (const float*)d_in[12];
  const float* attn_gn_b= (const float*)d_in[13];
  const float* attn_w2  = (const float*)d_in[14];
  const float* attn_b2  = (const float*)d_in[15];
  float* ws  = (float*)d_ws;
  float* out = (float*)d_out;

  hipMemsetAsync(ws, 0, 64*sizeof(float), stream);   // zero both stats regions
  k_stats1<<<dim3(NB*256), 256, 0, stream>>>(q_xyzs, k_xyzs, knn_idx, pre_w1, pre_b1, ws);
  k_fold1 <<<dim3(NB),      64, 0, stream>>>(pre_w1, pre_b1, pre_gn_w, pre_gn_b, ws);
  k_stats2<<<dim3(NB*256), 256, 0, stream>>>(q_xyzs, k_xyzs, knn_idx, pre_w2, pre_b2, attn_w1, attn_b1, ws);
  k_fold2 <<<dim3(NB),      64, 0, stream>>>(attn_w1, attn_b1, attn_gn_w, attn_gn_b, ws);
  k_final <<<dim3(NB*2048),256, 0, stream>>>(q_xyzs, k_xyzs, knn_idx, mask, pre_w2, pre_b2, attn_w2, attn_b2, ws, out);
}

// Round 2
// 1118.389 us; speedup vs baseline: 1.4065x; 1.4065x over previous
//
#include <hip/hip_runtime.h>
#include <hip/hip_bf16.h>
#include <math.h>

#define NB 4
#define NN 32768
#define MM 32768
#define KK 16
#define HID 64
#define DIM 32
#define ENK (NN*KK)              // 524288 elements per batch (power of 2, 2^19)
#define EF  524288.0f
#define CNTG (16.0f*EF)
#define NEG_HUGE (-3.4028234663852886e38f)

// ---- workspace float offsets (small region) ----
#define WS_STATS1 0        // [4][16] : slp[4], M10[10], pad
#define WS_STATS2 64       // [4][1056] : spe[32], Mpe[32*32]  (fallback uses first 8/b)
#define WS_W1F    4288     // [4][64][4]
#define WS_B1F    5312     // [4][64]
#define WS_WA1F   5568     // [4][64][32]
#define WS_BA1F   13760    // [4][64]
// small region ends at 14016 floats = 56064 B
#define PE_BYTE_OFF 65536ull
#define PE_BYTES (4ull*ENK*32ull*2ull)   // 134217728

// ---------------- helpers ----------------
template<int NV>
__device__ __forceinline__ void block_reduce_atomic(float* v, float* dst) {
  #pragma unroll
  for (int i = 0; i < NV; ++i) {
    float x = v[i];
    x += __shfl_down(x, 32);
    x += __shfl_down(x, 16);
    x += __shfl_down(x, 8);
    x += __shfl_down(x, 4);
    x += __shfl_down(x, 2);
    x += __shfl_down(x, 1);
    v[i] = x;
  }
  __shared__ float red[4][NV];
  const int lane = threadIdx.x & 63;
  const int wv = threadIdx.x >> 6;
  if (lane == 0) {
    #pragma unroll
    for (int i = 0; i < NV; ++i) red[wv][i] = v[i];
  }
  __syncthreads();
  if (threadIdx.x < NV) {
    float t = red[0][threadIdx.x] + red[1][threadIdx.x] +
              red[2][threadIdx.x] + red[3][threadIdx.x];
    atomicAdd(dst + threadIdx.x, t);
  }
}

__device__ __forceinline__ void compute_lp(const float* __restrict__ qb,
                                           const float* __restrict__ kb,
                                           int n, int idx,
                                           float& lp0, float& lp1, float& lp2, float& lp3) {
  float dx = kb[idx]        - qb[n];
  float dy = kb[MM + idx]   - qb[NN + n];
  float dz = kb[2*MM + idx] - qb[2*NN + n];
  float dist = sqrtf(fmaf(dx, dx, fmaf(dy, dy, dz*dz)));
  float inv = 1.0f / fmaxf(dist, 1e-12f);
  lp0 = dx * inv; lp1 = dy * inv; lp2 = dz * inv; lp3 = dist;
}

__device__ __forceinline__ unsigned pkbf(float a, float b) {
  union { __hip_bfloat16 h; unsigned short s; } ua, ub;
  ua.h = __float2bfloat16(a);
  ub.h = __float2bfloat16(b);
  return (unsigned)ua.s | ((unsigned)ub.s << 16);
}

__device__ __forceinline__ void unpack8(uint4 v, float* dst) {
  dst[0] = __uint_as_float(v.x << 16);
  dst[1] = __uint_as_float(v.x & 0xffff0000u);
  dst[2] = __uint_as_float(v.y << 16);
  dst[3] = __uint_as_float(v.y & 0xffff0000u);
  dst[4] = __uint_as_float(v.z << 16);
  dst[5] = __uint_as_float(v.z & 0xffff0000u);
  dst[6] = __uint_as_float(v.w << 16);
  dst[7] = __uint_as_float(v.w & 0xffff0000u);
}

// ---------------- Pass A: lp moments (14 accumulators per batch) ----------------
__global__ __launch_bounds__(256) void k_lpmom(
    const float* __restrict__ q_xyzs, const float* __restrict__ k_xyzs,
    const int* __restrict__ knn_idx, float* __restrict__ ws)
{
  const int b   = blockIdx.x >> 8;
  const int blk = blockIdx.x & 255;
  const float* qb = q_xyzs + b*3*NN;
  const float* kb = k_xyzs + b*3*MM;
  const int* idxb = knn_idx + b*ENK;

  float a[14];
  #pragma unroll
  for (int i = 0; i < 14; ++i) a[i] = 0.f;

  for (int it = 0; it < 8; ++it) {
    int el = (blk*8 + it)*256 + threadIdx.x;
    int n = el >> 4;
    int idx = idxb[el];
    float lp0, lp1, lp2, lp3;
    compute_lp(qb, kb, n, idx, lp0, lp1, lp2, lp3);
    a[0] += lp0; a[1] += lp1; a[2] += lp2; a[3] += lp3;
    a[4] = fmaf(lp0, lp0, a[4]);  a[5] = fmaf(lp0, lp1, a[5]);
    a[6] = fmaf(lp0, lp2, a[6]);  a[7] = fmaf(lp0, lp3, a[7]);
    a[8] = fmaf(lp1, lp1, a[8]);  a[9] = fmaf(lp1, lp2, a[9]);
    a[10] = fmaf(lp1, lp3, a[10]); a[11] = fmaf(lp2, lp2, a[11]);
    a[12] = fmaf(lp2, lp3, a[12]); a[13] = fmaf(lp3, lp3, a[13]);
  }
  block_reduce_atomic<14>(a, ws + WS_STATS1 + b*16);
}

// ---------------- Fold GN1 into W1 ----------------
__global__ __launch_bounds__(64) void k_fold1(
    const float* __restrict__ w1, const float* __restrict__ b1,
    const float* __restrict__ gw, const float* __restrict__ gb,
    float* __restrict__ ws)
{
  int b = blockIdx.x, o = threadIdx.x;
  const float* st = ws + WS_STATS1 + b*16;
  float4 w = ((const float4*)w1)[o];
  float bb = b1[o];
  float dot = w.x*st[0] + w.y*st[1] + w.z*st[2] + w.w*st[3];
  float quad = w.x*w.x*st[4] + w.y*w.y*st[8] + w.z*w.z*st[11] + w.w*w.w*st[13]
    + 2.f*(w.x*w.y*st[5] + w.x*w.z*st[6] + w.x*w.w*st[7]
         + w.y*w.z*st[9] + w.y*w.w*st[10] + w.z*w.w*st[12]);
  float sum = dot + EF*bb;
  float ssq = quad + 2.f*bb*dot + EF*bb*bb;
  #pragma unroll
  for (int m = 1; m < 16; m <<= 1) {
    sum += __shfl_xor(sum, m);
    ssq += __shfl_xor(ssq, m);
  }
  float mu  = sum / CNTG;
  float var = ssq / CNTG - mu*mu;
  float sc  = rsqrtf(var + 1e-5f) * gw[o];
  ((float4*)(ws + WS_W1F))[b*64 + o] = make_float4(w.x*sc, w.y*sc, w.z*sc, w.w*sc);
  (ws + WS_B1F)[b*64 + o] = (bb - mu)*sc + gb[o];
}

// ---------------- Pass B: compute pe, store bf16 (2 elements per thread) ----------------
__global__ __launch_bounds__(256) void k_pe(
    const float* __restrict__ q_xyzs, const float* __restrict__ k_xyzs,
    const int* __restrict__ knn_idx,
    const float* __restrict__ w2, const float* __restrict__ b2,
    const float* __restrict__ ws, __hip_bfloat16* __restrict__ pe_ws)
{
  const int ge0 = blockIdx.x*512 + threadIdx.x;
  const int ge1 = ge0 + 256;
  const int b = ge0 >> 19;
  const float* qb = q_xyzs + b*3*NN;
  const float* kb = k_xyzs + b*3*MM;

  int n0 = (ge0 & (ENK-1)) >> 4;
  int n1 = (ge1 & (ENK-1)) >> 4;
  int i0 = knn_idx[ge0];
  int i1 = knn_idx[ge1];
  float a0,a1,a2,a3, c0,c1,c2,c3;
  compute_lp(qb, kb, n0, i0, a0,a1,a2,a3);
  compute_lp(qb, kb, n1, i1, c0,c1,c2,c3);

  const float4* w1f = (const float4*)(ws + WS_W1F) + b*64;
  const float*  b1f = ws + WS_B1F + b*64;
  const float4* w2v = (const float4*)w2;

  float pe0[DIM], pe1[DIM];
  #pragma unroll
  for (int j = 0; j < DIM; ++j) { float t = b2[j]; pe0[j] = t; pe1[j] = t; }

  #pragma unroll
  for (int oc = 0; oc < 8; ++oc) {
    float h0[8], h1_[8];
    #pragma unroll
    for (int oo = 0; oo < 8; ++oo) {
      int o = oc*8 + oo;
      float4 w = w1f[o]; float bb = b1f[o];
      float x0 = fmaf(w.x, a0, fmaf(w.y, a1, fmaf(w.z, a2, fmaf(w.w, a3, bb))));
      float x1 = fmaf(w.x, c0, fmaf(w.y, c1, fmaf(w.z, c2, fmaf(w.w, c3, bb))));
      h0[oo]  = fmaxf(x0, 0.f);
      h1_[oo] = fmaxf(x1, 0.f);
    }
    #pragma unroll
    for (int j = 0; j < DIM; ++j) {
      float4 wA = w2v[j*16 + oc*2];
      float4 wB = w2v[j*16 + oc*2 + 1];
      float s0 = pe0[j], s1 = pe1[j];
      s0 = fmaf(wA.x, h0[0], s0); s0 = fmaf(wA.y, h0[1], s0);
      s0 = fmaf(wA.z, h0[2], s0); s0 = fmaf(wA.w, h0[3], s0);
      s0 = fmaf(wB.x, h0[4], s0); s0 = fmaf(wB.y, h0[5], s0);
      s0 = fmaf(wB.z, h0[6], s0); s0 = fmaf(wB.w, h0[7], s0);
      s1 = fmaf(wA.x, h1_[0], s1); s1 = fmaf(wA.y, h1_[1], s1);
      s1 = fmaf(wA.z, h1_[2], s1); s1 = fmaf(wA.w, h1_[3], s1);
      s1 = fmaf(wB.x, h1_[4], s1); s1 = fmaf(wB.y, h1_[5], s1);
      s1 = fmaf(wB.z, h1_[6], s1); s1 = fmaf(wB.w, h1_[7], s1);
      pe0[j] = s0; pe1[j] = s1;
    }
  }

  unsigned st0[16], st1[16];
  #pragma unroll
  for (int j = 0; j < 16; ++j) {
    st0[j] = pkbf(pe0[2*j], pe0[2*j+1]);
    st1[j] = pkbf(pe1[2*j], pe1[2*j+1]);
  }
  uint4* d0 = (uint4*)(pe_ws + (size_t)ge0*32);
  uint4* d1 = (uint4*)(pe_ws + (size_t)ge1*32);
  #pragma unroll
  for (int i = 0; i < 4; ++i) { d0[i] = ((uint4*)st0)[i]; d1[i] = ((uint4*)st1)[i]; }
}

// ---------------- Pass B2: pe second moments (32x32 + spe) via LDS tiles ----------------
__global__ __launch_bounds__(256) void k_pemom(
    const __hip_bfloat16* __restrict__ pe_ws, float* __restrict__ ws)
{
  __shared__ float tile[64][33];
  const int b   = blockIdx.x >> 7;     // 128 blocks per batch
  const int blk = blockIdx.x & 127;
  const size_t base = (size_t)b*ENK + (size_t)blk*4096;

  const int r = threadIdx.x >> 3;       // 0..31
  const int c = (threadIdx.x & 7) * 4;  // 0..28
  const int le = threadIdx.x >> 2;      // 0..63 (load element)
  const int lq = threadIdx.x & 3;       // 0..3  (load quarter)
  const bool dospe = threadIdx.x < 32;

  float acc0 = 0.f, acc1 = 0.f, acc2 = 0.f, acc3 = 0.f, accs = 0.f;

  for (int ch = 0; ch < 64; ++ch) {
    const uint4* src = (const uint4*)(pe_ws + (base + (size_t)(ch*64 + le))*32);
    uint4 v = src[lq];
    unpack8(v, &tile[le][lq*8]);
    __syncthreads();
    #pragma unroll 8
    for (int ee = 0; ee < 64; ++ee) {
      float vr = tile[ee][r];
      float v0 = tile[ee][c], v1 = tile[ee][c+1], v2 = tile[ee][c+2], v3 = tile[ee][c+3];
      acc0 = fmaf(vr, v0, acc0);
      acc1 = fmaf(vr, v1, acc1);
      acc2 = fmaf(vr, v2, acc2);
      acc3 = fmaf(vr, v3, acc3);
      if (dospe) accs += tile[ee][threadIdx.x];
    }
    __syncthreads();
  }
  float* st2 = ws + WS_STATS2 + b*1056;
  atomicAdd(st2 + 32 + r*32 + c + 0, acc0);
  atomicAdd(st2 + 32 + r*32 + c + 1, acc1);
  atomicAdd(st2 + 32 + r*32 + c + 2, acc2);
  atomicAdd(st2 + 32 + r*32 + c + 3, acc3);
  if (dospe) atomicAdd(st2 + threadIdx.x, accs);
}

// ---------------- Fold GN2 into Wa1 (moment version) ----------------
__global__ __launch_bounds__(64) void k_fold2m(
    const float* __restrict__ wa1, const float* __restrict__ ba1,
    const float* __restrict__ gw2, const float* __restrict__ gb2,
    float* __restrict__ ws)
{
  int b = blockIdx.x, o = threadIdx.x;
  const float* st = ws + WS_STATS2 + b*1056;   // spe[32], M[1024]
  float w[32];
  const float4* wrow = (const float4*)wa1 + o*8;
  #pragma unroll
  for (int i = 0; i < 8; ++i) {
    float4 t = wrow[i];
    w[4*i] = t.x; w[4*i+1] = t.y; w[4*i+2] = t.z; w[4*i+3] = t.w;
  }
  float dot = 0.f;
  #pragma unroll
  for (int cc = 0; cc < 32; ++cc) dot = fmaf(w[cc], st[cc], dot);
  float quad = 0.f;
  #pragma unroll
  for (int rr = 0; rr < 32; ++rr) {
    const float* Mr = st + 32 + rr*32;
    float mr = 0.f;
    #pragma unroll
    for (int cc = 0; cc < 32; ++cc) mr = fmaf(Mr[cc], w[cc], mr);
    quad = fmaf(w[rr], mr, quad);
  }
  float bb = ba1[o];
  float sum = dot + EF*bb;
  float ssq = quad + 2.f*bb*dot + EF*bb*bb;
  #pragma unroll
  for (int m = 1; m < 16; m <<= 1) {
    sum += __shfl_xor(sum, m);
    ssq += __shfl_xor(ssq, m);
  }
  float mu  = sum / CNTG;
  float var = ssq / CNTG - mu*mu;
  float sc  = rsqrtf(var + 1e-5f) * gw2[o];
  float4* dst = (float4*)(ws + WS_WA1F) + (b*64 + o)*8;
  #pragma unroll
  for (int i = 0; i < 8; ++i) {
    dst[i] = make_float4(w[4*i]*sc, w[4*i+1]*sc, w[4*i+2]*sc, w[4*i+3]*sc);
  }
  (ws + WS_BA1F)[b*64 + o] = (bb - mu)*sc + gb2[o];
}

// ---------------- Pass C: h2, logits, masked softmax, output ----------------
__global__ __launch_bounds__(256) void k_out(
    const __hip_bfloat16* __restrict__ pe_ws, const int* __restrict__ mask,
    const float* __restrict__ wa2, const float* __restrict__ ba2,
    const float* __restrict__ ws, float* __restrict__ out)
{
  const int e = blockIdx.x*256 + threadIdx.x;
  const int b = e >> 19;
  const int r = e & (ENK - 1);
  const int n = r >> 4;
  const int k = threadIdx.x & 15;

  float pe[DIM];
  const uint4* src = (const uint4*)(pe_ws + (size_t)e*32);
  #pragma unroll
  for (int i = 0; i < 4; ++i) { uint4 v = src[i]; unpack8(v, &pe[i*8]); }

  const float4* wa1f = (const float4*)(ws + WS_WA1F) + b*64*8;
  const float*  ba1f = ws + WS_BA1F + b*64;
  const float4* wa2v = (const float4*)wa2;

  float lg[DIM];
  #pragma unroll
  for (int j = 0; j < DIM; ++j) lg[j] = ba2[j];

  #pragma unroll
  for (int oc = 0; oc < 4; ++oc) {
    float h2c[16];
    #pragma unroll
    for (int oo = 0; oo < 16; ++oo) {
      int o = oc*16 + oo;
      float acc = ba1f[o];
      #pragma unroll
      for (int j4 = 0; j4 < 8; ++j4) {
        float4 w = wa1f[o*8 + j4];
        acc = fmaf(w.x, pe[4*j4+0], acc);
        acc = fmaf(w.y, pe[4*j4+1], acc);
        acc = fmaf(w.z, pe[4*j4+2], acc);
        acc = fmaf(w.w, pe[4*j4+3], acc);
      }
      h2c[oo] = fmaxf(acc, 0.f);
    }
    #pragma unroll
    for (int j = 0; j < DIM; ++j) {
      float s = lg[j];
      #pragma unroll
      for (int i = 0; i < 4; ++i) {
        float4 w = wa2v[j*16 + oc*4 + i];
        s = fmaf(w.x, h2c[4*i+0], s);
        s = fmaf(w.y, h2c[4*i+1], s);
        s = fmaf(w.z, h2c[4*i+2], s);
        s = fmaf(w.w, h2c[4*i+3], s);
      }
      lg[j] = s;
    }
  }

  const bool valid = mask[e] != 0;
  float* outb = out + b*(DIM*NN);

  #pragma unroll
  for (int j = 0; j < DIM; ++j) {
    float v = valid ? lg[j] : NEG_HUGE;
    float m = v;
    m = fmaxf(m, __shfl_xor(m, 1));
    m = fmaxf(m, __shfl_xor(m, 2));
    m = fmaxf(m, __shfl_xor(m, 4));
    m = fmaxf(m, __shfl_xor(m, 8));
    float p = __expf(v - m);
    float s = p;
    s += __shfl_xor(s, 1);
    s += __shfl_xor(s, 2);
    s += __shfl_xor(s, 4);
    s += __shfl_xor(s, 8);
    float cc = pe[j] * p;
    cc += __shfl_xor(cc, 1);
    cc += __shfl_xor(cc, 2);
    cc += __shfl_xor(cc, 4);
    cc += __shfl_xor(cc, 8);
    if (k == 0) outb[j*NN + n] = cc / s;
  }
}

// ================= fallback path (ws too small): round-1 verified kernels =================
__global__ __launch_bounds__(256) void k_stats2(
    const float* __restrict__ q_xyzs, const float* __restrict__ k_xyzs,
    const int* __restrict__ knn_idx,
    const float* __restrict__ w2, const float* __restrict__ b2,
    const float* __restrict__ wa1, const float* __restrict__ ba1,
    float* __restrict__ ws)
{
  const int b   = blockIdx.x >> 8;
  const int blk = blockIdx.x & 255;
  const float* qb  = q_xyzs + b*3*NN;
  const float* kb  = k_xyzs + b*3*MM;
  const int* idxb  = knn_idx + b*ENK;
  const float4* w1fv = (const float4*)(ws + WS_W1F) + b*64;
  const float*  b1fb = ws + WS_B1F + b*64;
  const float4* w2v  = (const float4*)w2;
  const float4* wa1v = (const float4*)wa1;

  float sacc[4] = {0.f,0.f,0.f,0.f};
  float qacc[4] = {0.f,0.f,0.f,0.f};

  for (int it = 0; it < 8; ++it) {
    int el = (blk*8 + it)*256 + threadIdx.x;
    int n = el >> 4;
    int idx = idxb[el];
    float lp0, lp1, lp2, lp3;
    compute_lp(qb, kb, n, idx, lp0, lp1, lp2, lp3);

    float h1[HID];
    #pragma unroll
    for (int o = 0; o < HID; ++o) {
      float4 w = w1fv[o];
      float x = fmaf(w.x, lp0, fmaf(w.y, lp1, fmaf(w.z, lp2, fmaf(w.w, lp3, b1fb[o]))));
      h1[o] = fmaxf(x, 0.f);
    }
    float pe[DIM];
    #pragma unroll
    for (int j = 0; j < DIM; ++j) {
      float acc = b2[j];
      #pragma unroll
      for (int o4 = 0; o4 < 16; ++o4) {
        float4 w = w2v[j*16 + o4];
        acc = fmaf(w.x, h1[4*o4+0], acc);
        acc = fmaf(w.y, h1[4*o4+1], acc);
        acc = fmaf(w.z, h1[4*o4+2], acc);
        acc = fmaf(w.w, h1[4*o4+3], acc);
      }
      pe[j] = acc;
    }
    #pragma unroll
    for (int g = 0; g < 4; ++g) {
      float sg = 0.f, qg = 0.f;
      #pragma unroll
      for (int oo = 0; oo < 16; ++oo) {
        int o = g*16 + oo;
        float acc = ba1[o];
        #pragma unroll
        for (int j4 = 0; j4 < 8; ++j4) {
          float4 w = wa1v[o*8 + j4];
          acc = fmaf(w.x, pe[4*j4+0], acc);
          acc = fmaf(w.y, pe[4*j4+1], acc);
          acc = fmaf(w.z, pe[4*j4+2], acc);
          acc = fmaf(w.w, pe[4*j4+3], acc);
        }
        sg += acc; qg += acc*acc;
      }
      sacc[g] += sg; qacc[g] += qg;
    }
  }
  float v[8] = {sacc[0],sacc[1],sacc[2],sacc[3],qacc[0],qacc[1],qacc[2],qacc[3]};
  block_reduce_atomic<8>(v, ws + WS_STATS2 + b*1056);
}

__global__ __launch_bounds__(64) void k_fold2d(
    const float* __restrict__ wa1, const float* __restrict__ ba1,
    const float* __restrict__ gw2, const float* __restrict__ gb2,
    float* __restrict__ ws)
{
  int b = blockIdx.x, o = threadIdx.x, g = o >> 4;
  const float* st = ws + WS_STATS2 + b*1056;
  float mu  = st[g] / CNTG;
  float var = st[4+g] / CNTG - mu*mu;
  float sc  = rsqrtf(var + 1e-5f) * gw2[o];
  float4* dst = (float4*)(ws + WS_WA1F) + (b*64 + o)*8;
  const float4* src = (const float4*)wa1 + o*8;
  #pragma unroll
  for (int j4 = 0; j4 < 8; ++j4) {
    float4 w = src[j4];
    dst[j4] = make_float4(w.x*sc, w.y*sc, w.z*sc, w.w*sc);
  }
  (ws + WS_BA1F)[b*64 + o] = (ba1[o] - mu)*sc + gb2[o];
}

__global__ __launch_bounds__(256) void k_final(
    const float* __restrict__ q_xyzs, const float* __restrict__ k_xyzs,
    const int* __restrict__ knn_idx, const int* __restrict__ mask,
    const float* __restrict__ w2, const float* __restrict__ b2,
    const float* __restrict__ wa2, const float* __restrict__ ba2,
    const float* __restrict__ ws, float* __restrict__ out)
{
  const int e = blockIdx.x*256 + threadIdx.x;
  const int b = e >> 19;
  const int r = e & (ENK - 1);
  const int n = r >> 4;
  const int k = threadIdx.x & 15;

  const float* qb = q_xyzs + b*3*NN;
  const float* kb = k_xyzs + b*3*MM;
  int idx = knn_idx[e];
  float lp0, lp1, lp2, lp3;
  compute_lp(qb, kb, n, idx, lp0, lp1, lp2, lp3);

  const float4* w1fv = (const float4*)(ws + WS_W1F) + b*64;
  const float*  b1fb = ws + WS_B1F + b*64;
  float h1[HID];
  #pragma unroll
  for (int o = 0; o < HID; ++o) {
    float4 w = w1fv[o];
    float x = fmaf(w.x, lp0, fmaf(w.y, lp1, fmaf(w.z, lp2, fmaf(w.w, lp3, b1fb[o]))));
    h1[o] = fmaxf(x, 0.f);
  }
  float pe[DIM];
  const float4* w2v = (const float4*)w2;
  #pragma unroll
  for (int j = 0; j < DIM; ++j) {
    float acc = b2[j];
    #pragma unroll
    for (int o4 = 0; o4 < 16; ++o4) {
      float4 w = w2v[j*16 + o4];
      acc = fmaf(w.x, h1[4*o4+0], acc);
      acc = fmaf(w.y, h1[4*o4+1], acc);
      acc = fmaf(w.z, h1[4*o4+2], acc);
      acc = fmaf(w.w, h1[4*o4+3], acc);
    }
    pe[j] = acc;
  }
  float h2[HID];
  const float4* wa1fv = (const float4*)(ws + WS_WA1F) + b*64*8;
  const float*  ba1fb = ws + WS_BA1F + b*64;
  #pragma unroll
  for (int o = 0; o < HID; ++o) {
    float acc = ba1fb[o];
    #pragma unroll
    for (int j4 = 0; j4 < 8; ++j4) {
      float4 w = wa1fv[o*8 + j4];
      acc = fmaf(w.x, pe[4*j4+0], acc);
      acc = fmaf(w.y, pe[4*j4+1], acc);
      acc = fmaf(w.z, pe[4*j4+2], acc);
      acc = fmaf(w.w, pe[4*j4+3], acc);
    }
    h2[o] = fmaxf(acc, 0.f);
  }
  float lg[DIM];
  const float4* wa2v = (const float4*)wa2;
  #pragma unroll
  for (int j = 0; j < DIM; ++j) {
    float acc = ba2[j];
    #pragma unroll
    for (int o4 = 0; o4 < 16; ++o4) {
      float4 w = wa2v[j*16 + o4];
      acc = fmaf(w.x, h2[4*o4+0], acc);
      acc = fmaf(w.y, h2[4*o4+1], acc);
      acc = fmaf(w.z, h2[4*o4+2], acc);
      acc = fmaf(w.w, h2[4*o4+3], acc);
    }
    lg[j] = acc;
  }

  const bool valid = mask[e] != 0;
  float* outb = out + b*(DIM*NN);

  #pragma unroll
  for (int j = 0; j < DIM; ++j) {
    float v = valid ? lg[j] : NEG_HUGE;
    float m = v;
    m = fmaxf(m, __shfl_xor(m, 1));
    m = fmaxf(m, __shfl_xor(m, 2));
    m = fmaxf(m, __shfl_xor(m, 4));
    m = fmaxf(m, __shfl_xor(m, 8));
    float p = __expf(v - m);
    float s = p;
    s += __shfl_xor(s, 1);
    s += __shfl_xor(s, 2);
    s += __shfl_xor(s, 4);
    s += __shfl_xor(s, 8);
    float c = pe[j] * p;
    c += __shfl_xor(c, 1);
    c += __shfl_xor(c, 2);
    c += __shfl_xor(c, 4);
    c += __shfl_xor(c, 8);
    if (k == 0) outb[j*NN + n] = c / s;
  }
}

extern "C" void kernel_launch(void* const* d_in, const int* in_sizes, int n_in,
                              void* d_out, int out_size, void* d_ws, size_t ws_size,
                              hipStream_t stream) {
  (void)in_sizes; (void)n_in; (void)out_size;
  const float* q_xyzs   = (const float*)d_in[0];
  const float* k_xyzs   = (const float*)d_in[1];
  const int*   knn_idx  = (const int*)d_in[2];
  const int*   mask     = (const int*)d_in[3];
  const float* pre_w1   = (const float*)d_in[4];
  const float* pre_b1   = (const float*)d_in[5];
  const float* pre_gn_w = (const float*)d_in[6];
  const float* pre_gn_b = (const float*)d_in[7];
  const float* pre_w2   = (const float*)d_in[8];
  const float* pre_b2   = (const float*)d_in[9];
  const float* attn_w1  = (const float*)d_in[10];
  const float* attn_b1  = (const float*)d_in[11];
  const float* attn_gn_w= (const float*)d_in[12];
  const float* attn_gn_b= (const float*)d_in[13];
  const float* attn_w2  = (const float*)d_in[14];
  const float* attn_b2  = (const float*)d_in[15];
  float* ws  = (float*)d_ws;
  float* out = (float*)d_out;
  __hip_bfloat16* pe_ws = (__hip_bfloat16*)((char*)d_ws + PE_BYTE_OFF);

  const bool big = ws_size >= (size_t)(PE_BYTE_OFF + PE_BYTES);

  hipMemsetAsync(ws, 0, (64 + 4*1056)*sizeof(float), stream);
  k_lpmom<<<dim3(NB*256), 256, 0, stream>>>(q_xyzs, k_xyzs, knn_idx, ws);
  k_fold1<<<dim3(NB),      64, 0, stream>>>(pre_w1, pre_b1, pre_gn_w, pre_gn_b, ws);

  if (big) {
    k_pe    <<<dim3(NB*1024), 256, 0, stream>>>(q_xyzs, k_xyzs, knn_idx, pre_w2, pre_b2, ws, pe_ws);
    k_pemom <<<dim3(NB*128),  256, 0, stream>>>(pe_ws, ws);
    k_fold2m<<<dim3(NB),       64, 0, stream>>>(attn_w1, attn_b1, attn_gn_w, attn_gn_b, ws);
    k_out   <<<dim3(NB*2048), 256, 0, stream>>>(pe_ws, mask, attn_w2, attn_b2, ws, out);
  } else {
    k_stats2<<<dim3(NB*256), 256, 0, stream>>>(q_xyzs, k_xyzs, knn_idx, pre_w2, pre_b2, attn_w1, attn_b1, ws);
    k_fold2d<<<dim3(NB),      64, 0, stream>>>(attn_w1, attn_b1, attn_gn_w, attn_gn_b, ws);
    k_final <<<dim3(NB*2048),256, 0, stream>>>(q_xyzs, k_xyzs, knn_idx, mask, pre_w2, pre_b2, attn_w2, attn_b2, ws, out);
  }
}

// Round 3
// 609.391 us; speedup vs baseline: 2.5813x; 1.8353x over previous
//
#include <hip/hip_runtime.h>
#include <hip/hip_bf16.h>
#include <math.h>

#define NB 4
#define NN 32768
#define MM 32768
#define KK 16
#define HID 64
#define DIM 32
#define ENK (NN*KK)              // 524288 elements per batch (2^19)
#define EF  524288.0f
#define CNTG (16.0f*EF)
#define NEG_HUGE (-3.4028234663852886e38f)

// ---- workspace u32/float offsets (small region) ----
#define WS_STATS1 0        // [4][16]  : slp[4], M10[10], pad
#define WS_STATS2 64       // [4][1056]: spe[32], Mpe[32*32]
#define WS_W1F    4288     // [4][64][4] f32 folded pre_w1
#define WS_B1F    5312     // [4][64] f32
#define WS_WA1H   5568     // [4][64][16] u32 (half2-packed folded attn_w1)
#define WS_BA1F   9664     // [4][64] f32
#define WS_W2H    9920     // [32][32] u32 (half2-packed pre_w2)
#define WS_WA2H   10944    // [32][32] u32 (half2-packed attn_w2)
// ends 11968 floats = 47872 B < 65536
#define PE_BYTE_OFF 65536ull

typedef _Float16 h2v __attribute__((ext_vector_type(2)));

#if defined(__has_builtin)
#if __has_builtin(__builtin_amdgcn_fdot2)
#define USE_FDOT2 1
#endif
#endif
#ifndef USE_FDOT2
#define USE_FDOT2 0
#endif

__device__ __forceinline__ float dot2f(unsigned w, unsigned x, float acc) {
#if USE_FDOT2
  return __builtin_amdgcn_fdot2(__builtin_bit_cast(h2v, w),
                                __builtin_bit_cast(h2v, x), acc, false);
#else
  h2v a = __builtin_bit_cast(h2v, w);
  h2v b = __builtin_bit_cast(h2v, x);
  acc = fmaf((float)a[0], (float)b[0], acc);
  return fmaf((float)a[1], (float)b[1], acc);
#endif
}

__device__ __forceinline__ unsigned pkh(float a, float b) {
  return __builtin_bit_cast(unsigned, __builtin_amdgcn_cvt_pkrtz(a, b));
}

__device__ __forceinline__ void unpackh8(uint4 v, float* d) {
  h2v a = __builtin_bit_cast(h2v, v.x);
  h2v b = __builtin_bit_cast(h2v, v.y);
  h2v c = __builtin_bit_cast(h2v, v.z);
  h2v e = __builtin_bit_cast(h2v, v.w);
  d[0] = (float)a[0]; d[1] = (float)a[1];
  d[2] = (float)b[0]; d[3] = (float)b[1];
  d[4] = (float)c[0]; d[5] = (float)c[1];
  d[6] = (float)e[0]; d[7] = (float)e[1];
}

template<int NV>
__device__ __forceinline__ void block_reduce_atomic(float* v, float* dst) {
  #pragma unroll
  for (int i = 0; i < NV; ++i) {
    float x = v[i];
    x += __shfl_down(x, 32);
    x += __shfl_down(x, 16);
    x += __shfl_down(x, 8);
    x += __shfl_down(x, 4);
    x += __shfl_down(x, 2);
    x += __shfl_down(x, 1);
    v[i] = x;
  }
  __shared__ float red[4][NV];
  const int lane = threadIdx.x & 63;
  const int wv = threadIdx.x >> 6;
  if (lane == 0) {
    #pragma unroll
    for (int i = 0; i < NV; ++i) red[wv][i] = v[i];
  }
  __syncthreads();
  if (threadIdx.x < NV) {
    float t = red[0][threadIdx.x] + red[1][threadIdx.x] +
              red[2][threadIdx.x] + red[3][threadIdx.x];
    atomicAdd(dst + threadIdx.x, t);
  }
}

__device__ __forceinline__ void compute_lp(const float* __restrict__ qb,
                                           const float* __restrict__ kb,
                                           int n, int idx,
                                           float& lp0, float& lp1, float& lp2, float& lp3) {
  float dx = kb[idx]        - qb[n];
  float dy = kb[MM + idx]   - qb[NN + n];
  float dz = kb[2*MM + idx] - qb[2*NN + n];
  float dist = sqrtf(fmaf(dx, dx, fmaf(dy, dy, dz*dz)));
  float inv = 1.0f / fmaxf(dist, 1e-12f);
  lp0 = dx * inv; lp1 = dy * inv; lp2 = dz * inv; lp3 = dist;
}

// ---------------- Pass A: lp moments ----------------
__global__ __launch_bounds__(256) void k_lpmom(
    const float* __restrict__ q_xyzs, const float* __restrict__ k_xyzs,
    const int* __restrict__ knn_idx, float* __restrict__ ws)
{
  const int b   = blockIdx.x >> 8;
  const int blk = blockIdx.x & 255;
  const float* qb = q_xyzs + b*3*NN;
  const float* kb = k_xyzs + b*3*MM;
  const int* idxb = knn_idx + b*ENK;

  float a[14];
  #pragma unroll
  for (int i = 0; i < 14; ++i) a[i] = 0.f;

  for (int it = 0; it < 8; ++it) {
    int el = (blk*8 + it)*256 + threadIdx.x;
    int n = el >> 4;
    int idx = idxb[el];
    float lp0, lp1, lp2, lp3;
    compute_lp(qb, kb, n, idx, lp0, lp1, lp2, lp3);
    a[0] += lp0; a[1] += lp1; a[2] += lp2; a[3] += lp3;
    a[4] = fmaf(lp0, lp0, a[4]);  a[5] = fmaf(lp0, lp1, a[5]);
    a[6] = fmaf(lp0, lp2, a[6]);  a[7] = fmaf(lp0, lp3, a[7]);
    a[8] = fmaf(lp1, lp1, a[8]);  a[9] = fmaf(lp1, lp2, a[9]);
    a[10] = fmaf(lp1, lp3, a[10]); a[11] = fmaf(lp2, lp2, a[11]);
    a[12] = fmaf(lp2, lp3, a[12]); a[13] = fmaf(lp3, lp3, a[13]);
  }
  block_reduce_atomic<14>(a, ws + WS_STATS1 + b*16);
}

// ---------------- Fold GN1 into W1 ----------------
__global__ __launch_bounds__(64) void k_fold1(
    const float* __restrict__ w1, const float* __restrict__ b1,
    const float* __restrict__ gw, const float* __restrict__ gb,
    float* __restrict__ ws)
{
  int b = blockIdx.x, o = threadIdx.x;
  const float* st = ws + WS_STATS1 + b*16;
  float4 w = ((const float4*)w1)[o];
  float bb = b1[o];
  float dot = w.x*st[0] + w.y*st[1] + w.z*st[2] + w.w*st[3];
  float quad = w.x*w.x*st[4] + w.y*w.y*st[8] + w.z*w.z*st[11] + w.w*w.w*st[13]
    + 2.f*(w.x*w.y*st[5] + w.x*w.z*st[6] + w.x*w.w*st[7]
         + w.y*w.z*st[9] + w.y*w.w*st[10] + w.z*w.w*st[12]);
  float sum = dot + EF*bb;
  float ssq = quad + 2.f*bb*dot + EF*bb*bb;
  #pragma unroll
  for (int m = 1; m < 16; m <<= 1) {
    sum += __shfl_xor(sum, m);
    ssq += __shfl_xor(ssq, m);
  }
  float mu  = sum / CNTG;
  float var = ssq / CNTG - mu*mu;
  float sc  = rsqrtf(var + 1e-5f) * gw[o];
  ((float4*)(ws + WS_W1F))[b*64 + o] = make_float4(w.x*sc, w.y*sc, w.z*sc, w.w*sc);
  (ws + WS_B1F)[b*64 + o] = (bb - mu)*sc + gb[o];
}

// ---------------- pack batch-independent weights to half2 ----------------
__global__ __launch_bounds__(64) void k_packw(
    const float* __restrict__ w2, const float* __restrict__ wa2,
    unsigned* __restrict__ wsu)
{
  int t = threadIdx.x;
  if (t < 32) {
    const float* src = w2 + t*64;
    unsigned* dst = wsu + WS_W2H + t*32;
    #pragma unroll
    for (int i = 0; i < 32; ++i) dst[i] = pkh(src[2*i], src[2*i+1]);
  } else {
    int j = t - 32;
    const float* src = wa2 + j*64;
    unsigned* dst = wsu + WS_WA2H + j*32;
    #pragma unroll
    for (int i = 0; i < 32; ++i) dst[i] = pkh(src[2*i], src[2*i+1]);
  }
}

// ---------------- Pass B: compute pe, store f16 (2 elements/thread) ----------------
__global__ __launch_bounds__(256) void k_pe(
    const float* __restrict__ q_xyzs, const float* __restrict__ k_xyzs,
    const int* __restrict__ knn_idx, const float* __restrict__ b2,
    const float* __restrict__ ws, unsigned short* __restrict__ peh_ws)
{
  const int b = blockIdx.x >> 10;                 // 1024 blocks per batch (uniform!)
  const int ge0 = blockIdx.x*512 + threadIdx.x;
  const int ge1 = ge0 + 256;
  const float* qb = q_xyzs + b*3*NN;
  const float* kb = k_xyzs + b*3*MM;

  int n0 = (ge0 & (ENK-1)) >> 4;
  int n1 = (ge1 & (ENK-1)) >> 4;
  int i0 = knn_idx[ge0];
  int i1 = knn_idx[ge1];
  float a0,a1,a2,a3, c0,c1,c2,c3;
  compute_lp(qb, kb, n0, i0, a0,a1,a2,a3);
  compute_lp(qb, kb, n1, i1, c0,c1,c2,c3);

  const float4* w1f = (const float4*)(ws + WS_W1F) + b*64;   // SGPR-based
  const float*  b1f = ws + WS_B1F + b*64;

  unsigned h0h[32], h1h[32];
  #pragma unroll
  for (int o2 = 0; o2 < 32; ++o2) {
    float4 wA = w1f[2*o2];   float bA = b1f[2*o2];
    float4 wB = w1f[2*o2+1]; float bB = b1f[2*o2+1];
    float xA0 = fmaxf(fmaf(wA.x, a0, fmaf(wA.y, a1, fmaf(wA.z, a2, fmaf(wA.w, a3, bA)))), 0.f);
    float xB0 = fmaxf(fmaf(wB.x, a0, fmaf(wB.y, a1, fmaf(wB.z, a2, fmaf(wB.w, a3, bB)))), 0.f);
    float xA1 = fmaxf(fmaf(wA.x, c0, fmaf(wA.y, c1, fmaf(wA.z, c2, fmaf(wA.w, c3, bA)))), 0.f);
    float xB1 = fmaxf(fmaf(wB.x, c0, fmaf(wB.y, c1, fmaf(wB.z, c2, fmaf(wB.w, c3, bB)))), 0.f);
    h0h[o2] = pkh(xA0, xB0);
    h1h[o2] = pkh(xA1, xB1);
  }

  const unsigned* w2h = (const unsigned*)ws + WS_W2H;
  float pe0[DIM], pe1[DIM];
  #pragma unroll
  for (int j = 0; j < DIM; ++j) {
    float s0 = b2[j], s1 = b2[j];
    #pragma unroll
    for (int i2 = 0; i2 < 32; ++i2) {
      unsigned w = w2h[j*32 + i2];
      s0 = dot2f(w, h0h[i2], s0);
      s1 = dot2f(w, h1h[i2], s1);
    }
    pe0[j] = s0; pe1[j] = s1;
  }

  unsigned st0[16], st1[16];
  #pragma unroll
  for (int j = 0; j < 16; ++j) {
    st0[j] = pkh(pe0[2*j], pe0[2*j+1]);
    st1[j] = pkh(pe1[2*j], pe1[2*j+1]);
  }
  uint4* d0 = (uint4*)(peh_ws + (size_t)ge0*32);
  uint4* d1 = (uint4*)(peh_ws + (size_t)ge1*32);
  #pragma unroll
  for (int i = 0; i < 4; ++i) { d0[i] = ((uint4*)st0)[i]; d1[i] = ((uint4*)st1)[i]; }
}

// ---------------- Pass B2: pe moments via LDS tiles ----------------
__global__ __launch_bounds__(256) void k_pemom(
    const unsigned short* __restrict__ peh_ws, float* __restrict__ ws)
{
  __shared__ float tile[64][33];
  const int b   = blockIdx.x >> 7;     // 128 blocks per batch
  const int blk = blockIdx.x & 127;
  const size_t base = (size_t)b*ENK + (size_t)blk*4096;

  const int r = threadIdx.x >> 3;
  const int c = (threadIdx.x & 7) * 4;
  const int le = threadIdx.x >> 2;
  const int lq = threadIdx.x & 3;
  const bool dospe = threadIdx.x < 32;

  float acc0 = 0.f, acc1 = 0.f, acc2 = 0.f, acc3 = 0.f, accs = 0.f;

  for (int ch = 0; ch < 64; ++ch) {
    const uint4* src = (const uint4*)(peh_ws + (base + (size_t)(ch*64 + le))*32);
    uint4 v = src[lq];
    unpackh8(v, &tile[le][lq*8]);
    __syncthreads();
    #pragma unroll 8
    for (int ee = 0; ee < 64; ++ee) {
      float vr = tile[ee][r];
      acc0 = fmaf(vr, tile[ee][c+0], acc0);
      acc1 = fmaf(vr, tile[ee][c+1], acc1);
      acc2 = fmaf(vr, tile[ee][c+2], acc2);
      acc3 = fmaf(vr, tile[ee][c+3], acc3);
      if (dospe) accs += tile[ee][threadIdx.x];
    }
    __syncthreads();
  }
  float* st2 = ws + WS_STATS2 + b*1056;
  atomicAdd(st2 + 32 + r*32 + c + 0, acc0);
  atomicAdd(st2 + 32 + r*32 + c + 1, acc1);
  atomicAdd(st2 + 32 + r*32 + c + 2, acc2);
  atomicAdd(st2 + 32 + r*32 + c + 3, acc3);
  if (dospe) atomicAdd(st2 + threadIdx.x, accs);
}

// ---------------- Fold GN2 into Wa1, write half2-packed ----------------
__global__ __launch_bounds__(64) void k_fold2m(
    const float* __restrict__ wa1, const float* __restrict__ ba1,
    const float* __restrict__ gw2, const float* __restrict__ gb2,
    float* __restrict__ ws)
{
  int b = blockIdx.x, o = threadIdx.x;
  const float* st = ws + WS_STATS2 + b*1056;
  float w[32];
  const float4* wrow = (const float4*)wa1 + o*8;
  #pragma unroll
  for (int i = 0; i < 8; ++i) {
    float4 t = wrow[i];
    w[4*i] = t.x; w[4*i+1] = t.y; w[4*i+2] = t.z; w[4*i+3] = t.w;
  }
  float dot = 0.f;
  #pragma unroll
  for (int cc = 0; cc < 32; ++cc) dot = fmaf(w[cc], st[cc], dot);
  float quad = 0.f;
  #pragma unroll
  for (int rr = 0; rr < 32; ++rr) {
    const float* Mr = st + 32 + rr*32;
    float mr = 0.f;
    #pragma unroll
    for (int cc = 0; cc < 32; ++cc) mr = fmaf(Mr[cc], w[cc], mr);
    quad = fmaf(w[rr], mr, quad);
  }
  float bb = ba1[o];
  float sum = dot + EF*bb;
  float ssq = quad + 2.f*bb*dot + EF*bb*bb;
  #pragma unroll
  for (int m = 1; m < 16; m <<= 1) {
    sum += __shfl_xor(sum, m);
    ssq += __shfl_xor(ssq, m);
  }
  float mu  = sum / CNTG;
  float var = ssq / CNTG - mu*mu;
  float sc  = rsqrtf(var + 1e-5f) * gw2[o];
  unsigned* dst = (unsigned*)ws + WS_WA1H + (b*64 + o)*16;
  #pragma unroll
  for (int i2 = 0; i2 < 16; ++i2) dst[i2] = pkh(w[2*i2]*sc, w[2*i2+1]*sc);
  (ws + WS_BA1F)[b*64 + o] = (bb - mu)*sc + gb2[o];
}

// ---------------- Pass C: h2, logits, masked softmax, output ----------------
__global__ __launch_bounds__(256) void k_out(
    const unsigned short* __restrict__ peh_ws, const int* __restrict__ mask,
    const float* __restrict__ ba2,
    const float* __restrict__ ws, float* __restrict__ out)
{
  const int b = blockIdx.x >> 11;                // 2048 blocks per batch (uniform!)
  const int e = blockIdx.x*256 + threadIdx.x;
  const int n = (e & (ENK - 1)) >> 4;
  const int k = threadIdx.x & 15;

  unsigned peh[16];
  const uint4* src = (const uint4*)(peh_ws + (size_t)e*32);
  #pragma unroll
  for (int i = 0; i < 4; ++i) ((uint4*)peh)[i] = src[i];

  const unsigned* wa1h = (const unsigned*)ws + WS_WA1H + b*1024;
  const float*    ba1f = ws + WS_BA1F + b*64;
  const unsigned* wa2h = (const unsigned*)ws + WS_WA2H;

  unsigned h2h[32];
  #pragma unroll
  for (int oc = 0; oc < 4; ++oc) {
    float h2c[16];
    #pragma unroll
    for (int oo = 0; oo < 16; ++oo) {
      int o = oc*16 + oo;
      float acc = ba1f[o];
      #pragma unroll
      for (int i = 0; i < 16; ++i) acc = dot2f(wa1h[o*16 + i], peh[i], acc);
      h2c[oo] = fmaxf(acc, 0.f);
    }
    #pragma unroll
    for (int p = 0; p < 8; ++p) h2h[oc*8 + p] = pkh(h2c[2*p], h2c[2*p+1]);
  }

  float lg[DIM];
  #pragma unroll
  for (int j = 0; j < DIM; ++j) {
    float acc = ba2[j];
    #pragma unroll
    for (int i2 = 0; i2 < 32; ++i2) acc = dot2f(wa2h[j*32 + i2], h2h[i2], acc);
    lg[j] = acc;
  }

  const bool valid = mask[e] != 0;
  float* outb = out + b*(DIM*NN);

  #pragma unroll
  for (int j = 0; j < DIM; ++j) {
    float v = valid ? lg[j] : NEG_HUGE;
    float m = v;
    m = fmaxf(m, __shfl_xor(m, 1));
    m = fmaxf(m, __shfl_xor(m, 2));
    m = fmaxf(m, __shfl_xor(m, 4));
    m = fmaxf(m, __shfl_xor(m, 8));
    float p = __expf(v - m);
    float s = p;
    s += __shfl_xor(s, 1);
    s += __shfl_xor(s, 2);
    s += __shfl_xor(s, 4);
    s += __shfl_xor(s, 8);
    h2v hp = __builtin_bit_cast(h2v, peh[j >> 1]);
    float pej = (float)hp[j & 1];
    float cc = pej * p;
    cc += __shfl_xor(cc, 1);
    cc += __shfl_xor(cc, 2);
    cc += __shfl_xor(cc, 4);
    cc += __shfl_xor(cc, 8);
    if (k == 0) outb[j*NN + n] = cc / s;
  }
}

extern "C" void kernel_launch(void* const* d_in, const int* in_sizes, int n_in,
                              void* d_out, int out_size, void* d_ws, size_t ws_size,
                              hipStream_t stream) {
  (void)in_sizes; (void)n_in; (void)out_size; (void)ws_size;
  const float* q_xyzs   = (const float*)d_in[0];
  const float* k_xyzs   = (const float*)d_in[1];
  const int*   knn_idx  = (const int*)d_in[2];
  const int*   mask     = (const int*)d_in[3];
  const float* pre_w1   = (const float*)d_in[4];
  const float* pre_b1   = (const float*)d_in[5];
  const float* pre_gn_w = (const float*)d_in[6];
  const float* pre_gn_b = (const float*)d_in[7];
  const float* pre_w2   = (const float*)d_in[8];
  const float* pre_b2   = (const float*)d_in[9];
  const float* attn_w1  = (const float*)d_in[10];
  const float* attn_b1  = (const float*)d_in[11];
  const float* attn_gn_w= (const float*)d_in[12];
  const float* attn_gn_b= (const float*)d_in[13];
  const float* attn_w2  = (const float*)d_in[14];
  const float* attn_b2  = (const float*)d_in[15];
  float* ws  = (float*)d_ws;
  float* out = (float*)d_out;
  unsigned short* peh_ws = (unsigned short*)((char*)d_ws + PE_BYTE_OFF);

  hipMemsetAsync(ws, 0, (64 + 4*1056)*sizeof(float), stream);
  k_packw <<<dim3(1),        64, 0, stream>>>(pre_w2, attn_w2, (unsigned*)ws);
  k_lpmom <<<dim3(NB*256),  256, 0, stream>>>(q_xyzs, k_xyzs, knn_idx, ws);
  k_fold1 <<<dim3(NB),       64, 0, stream>>>(pre_w1, pre_b1, pre_gn_w, pre_gn_b, ws);
  k_pe    <<<dim3(NB*1024), 256, 0, stream>>>(q_xyzs, k_xyzs, knn_idx, pre_b2, ws, peh_ws);
  k_pemom <<<dim3(NB*128),  256, 0, stream>>>(peh_ws, ws);
  k_fold2m<<<dim3(NB),       64, 0, stream>>>(attn_w1, attn_b1, attn_gn_w, attn_gn_b, ws);
  k_out   <<<dim3(NB*2048), 256, 0, stream>>>(peh_ws, mask, attn_b2, ws, out);
}

// Round 4
// 379.891 us; speedup vs baseline: 4.1407x; 1.6041x over previous
//
#include <hip/hip_runtime.h>
#include <hip/hip_bf16.h>
#include <math.h>

#define NB 4
#define NN 32768
#define MM 32768
#define KK 16
#define HID 64
#define DIM 32
#define ENK (NN*KK)              // 524288 elements per batch (2^19)
#define EF  524288.0f
#define CNTG (16.0f*EF)
#define NEG_HUGE (-3.4028234663852886e38f)

// ---- workspace u32/float offsets (small region) ----
#define WS_STATS1 0        // [4][16]  : slp[4], M10[10], pad
#define WS_STATS2 64       // [4][1056]: spe[32], Mpe[32*32]
#define WS_W1F    4288     // [4][64][4] f32 folded pre_w1
#define WS_B1F    5312     // [4][64] f32
#define WS_WA1H   5568     // [4][64][16] u32 (half2-packed folded attn_w1)
#define WS_BA1F   9664     // [4][64] f32
#define WS_W2H    9920     // [32][32] u32 (half2-packed pre_w2)
#define WS_WA2H   10944    // [32][32] u32 (half2-packed attn_w2)
// ends 11968 floats = 47872 B < 65536
#define PE_BYTE_OFF 65536ull

typedef _Float16 h2v __attribute__((ext_vector_type(2)));
typedef _Float16 h8v __attribute__((ext_vector_type(8)));
typedef float f16v __attribute__((ext_vector_type(16)));

#if defined(__has_builtin)
#if __has_builtin(__builtin_amdgcn_fdot2)
#define USE_FDOT2 1
#endif
#endif
#ifndef USE_FDOT2
#define USE_FDOT2 0
#endif

__device__ __forceinline__ float dot2f(unsigned w, unsigned x, float acc) {
#if USE_FDOT2
  return __builtin_amdgcn_fdot2(__builtin_bit_cast(h2v, w),
                                __builtin_bit_cast(h2v, x), acc, false);
#else
  h2v a = __builtin_bit_cast(h2v, w);
  h2v b = __builtin_bit_cast(h2v, x);
  acc = fmaf((float)a[0], (float)b[0], acc);
  return fmaf((float)a[1], (float)b[1], acc);
#endif
}

__device__ __forceinline__ unsigned pkh(float a, float b) {
  return __builtin_bit_cast(unsigned, __builtin_amdgcn_cvt_pkrtz(a, b));
}

template<int NV>
__device__ __forceinline__ void block_reduce_atomic(float* v, float* dst) {
  #pragma unroll
  for (int i = 0; i < NV; ++i) {
    float x = v[i];
    x += __shfl_down(x, 32);
    x += __shfl_down(x, 16);
    x += __shfl_down(x, 8);
    x += __shfl_down(x, 4);
    x += __shfl_down(x, 2);
    x += __shfl_down(x, 1);
    v[i] = x;
  }
  __shared__ float red[4][NV];
  const int lane = threadIdx.x & 63;
  const int wv = threadIdx.x >> 6;
  if (lane == 0) {
    #pragma unroll
    for (int i = 0; i < NV; ++i) red[wv][i] = v[i];
  }
  __syncthreads();
  if (threadIdx.x < NV) {
    float t = red[0][threadIdx.x] + red[1][threadIdx.x] +
              red[2][threadIdx.x] + red[3][threadIdx.x];
    atomicAdd(dst + threadIdx.x, t);
  }
}

__device__ __forceinline__ void compute_lp(const float* __restrict__ qb,
                                           const float* __restrict__ kb,
                                           int n, int idx,
                                           float& lp0, float& lp1, float& lp2, float& lp3) {
  float dx = kb[idx]        - qb[n];
  float dy = kb[MM + idx]   - qb[NN + n];
  float dz = kb[2*MM + idx] - qb[2*NN + n];
  float dist = sqrtf(fmaf(dx, dx, fmaf(dy, dy, dz*dz)));
  float inv = 1.0f / fmaxf(dist, 1e-12f);
  lp0 = dx * inv; lp1 = dy * inv; lp2 = dz * inv; lp3 = dist;
}

// ---------------- Pass A: lp moments ----------------
__global__ __launch_bounds__(256) void k_lpmom(
    const float* __restrict__ q_xyzs, const float* __restrict__ k_xyzs,
    const int* __restrict__ knn_idx, float* __restrict__ ws)
{
  const int b   = blockIdx.x >> 8;
  const int blk = blockIdx.x & 255;
  const float* qb = q_xyzs + b*3*NN;
  const float* kb = k_xyzs + b*3*MM;
  const int* idxb = knn_idx + b*ENK;

  float a[14];
  #pragma unroll
  for (int i = 0; i < 14; ++i) a[i] = 0.f;

  for (int it = 0; it < 8; ++it) {
    int el = (blk*8 + it)*256 + threadIdx.x;
    int n = el >> 4;
    int idx = idxb[el];
    float lp0, lp1, lp2, lp3;
    compute_lp(qb, kb, n, idx, lp0, lp1, lp2, lp3);
    a[0] += lp0; a[1] += lp1; a[2] += lp2; a[3] += lp3;
    a[4] = fmaf(lp0, lp0, a[4]);  a[5] = fmaf(lp0, lp1, a[5]);
    a[6] = fmaf(lp0, lp2, a[6]);  a[7] = fmaf(lp0, lp3, a[7]);
    a[8] = fmaf(lp1, lp1, a[8]);  a[9] = fmaf(lp1, lp2, a[9]);
    a[10] = fmaf(lp1, lp3, a[10]); a[11] = fmaf(lp2, lp2, a[11]);
    a[12] = fmaf(lp2, lp3, a[12]); a[13] = fmaf(lp3, lp3, a[13]);
  }
  block_reduce_atomic<14>(a, ws + WS_STATS1 + b*16);
}

// ---------------- Fold GN1 into W1 ----------------
__global__ __launch_bounds__(64) void k_fold1(
    const float* __restrict__ w1, const float* __restrict__ b1,
    const float* __restrict__ gw, const float* __restrict__ gb,
    float* __restrict__ ws)
{
  int b = blockIdx.x, o = threadIdx.x;
  const float* st = ws + WS_STATS1 + b*16;
  float4 w = ((const float4*)w1)[o];
  float bb = b1[o];
  float dot = w.x*st[0] + w.y*st[1] + w.z*st[2] + w.w*st[3];
  float quad = w.x*w.x*st[4] + w.y*w.y*st[8] + w.z*w.z*st[11] + w.w*w.w*st[13]
    + 2.f*(w.x*w.y*st[5] + w.x*w.z*st[6] + w.x*w.w*st[7]
         + w.y*w.z*st[9] + w.y*w.w*st[10] + w.z*w.w*st[12]);
  float sum = dot + EF*bb;
  float ssq = quad + 2.f*bb*dot + EF*bb*bb;
  #pragma unroll
  for (int m = 1; m < 16; m <<= 1) {
    sum += __shfl_xor(sum, m);
    ssq += __shfl_xor(ssq, m);
  }
  float mu  = sum / CNTG;
  float var = ssq / CNTG - mu*mu;
  float sc  = rsqrtf(var + 1e-5f) * gw[o];
  ((float4*)(ws + WS_W1F))[b*64 + o] = make_float4(w.x*sc, w.y*sc, w.z*sc, w.w*sc);
  (ws + WS_B1F)[b*64 + o] = (bb - mu)*sc + gb[o];
}

// ---------------- pack batch-independent weights to half2 ----------------
__global__ __launch_bounds__(64) void k_packw(
    const float* __restrict__ w2, const float* __restrict__ wa2,
    unsigned* __restrict__ wsu)
{
  int t = threadIdx.x;
  if (t < 32) {
    const float* src = w2 + t*64;
    unsigned* dst = wsu + WS_W2H + t*32;
    #pragma unroll
    for (int i = 0; i < 32; ++i) dst[i] = pkh(src[2*i], src[2*i+1]);
  } else {
    int j = t - 32;
    const float* src = wa2 + j*64;
    unsigned* dst = wsu + WS_WA2H + j*32;
    #pragma unroll
    for (int i = 0; i < 32; ++i) dst[i] = pkh(src[2*i], src[2*i+1]);
  }
}

// ---------------- Pass B: compute pe, store f16 (2 elements/thread) ----------------
__global__ __launch_bounds__(256) void k_pe(
    const float* __restrict__ q_xyzs, const float* __restrict__ k_xyzs,
    const int* __restrict__ knn_idx, const float* __restrict__ b2,
    const float* __restrict__ ws, unsigned short* __restrict__ peh_ws)
{
  const int b = blockIdx.x >> 10;                 // 1024 blocks per batch (uniform!)
  const int ge0 = blockIdx.x*512 + threadIdx.x;
  const int ge1 = ge0 + 256;
  const float* qb = q_xyzs + b*3*NN;
  const float* kb = k_xyzs + b*3*MM;

  int n0 = (ge0 & (ENK-1)) >> 4;
  int n1 = (ge1 & (ENK-1)) >> 4;
  int i0 = knn_idx[ge0];
  int i1 = knn_idx[ge1];
  float a0,a1,a2,a3, c0,c1,c2,c3;
  compute_lp(qb, kb, n0, i0, a0,a1,a2,a3);
  compute_lp(qb, kb, n1, i1, c0,c1,c2,c3);

  const float4* w1f = (const float4*)(ws + WS_W1F) + b*64;   // SGPR-based
  const float*  b1f = ws + WS_B1F + b*64;

  unsigned h0h[32], h1h[32];
  #pragma unroll
  for (int o2 = 0; o2 < 32; ++o2) {
    float4 wA = w1f[2*o2];   float bA = b1f[2*o2];
    float4 wB = w1f[2*o2+1]; float bB = b1f[2*o2+1];
    float xA0 = fmaxf(fmaf(wA.x, a0, fmaf(wA.y, a1, fmaf(wA.z, a2, fmaf(wA.w, a3, bA)))), 0.f);
    float xB0 = fmaxf(fmaf(wB.x, a0, fmaf(wB.y, a1, fmaf(wB.z, a2, fmaf(wB.w, a3, bB)))), 0.f);
    float xA1 = fmaxf(fmaf(wA.x, c0, fmaf(wA.y, c1, fmaf(wA.z, c2, fmaf(wA.w, c3, bA)))), 0.f);
    float xB1 = fmaxf(fmaf(wB.x, c0, fmaf(wB.y, c1, fmaf(wB.z, c2, fmaf(wB.w, c3, bB)))), 0.f);
    h0h[o2] = pkh(xA0, xB0);
    h1h[o2] = pkh(xA1, xB1);
  }

  const unsigned* w2h = (const unsigned*)ws + WS_W2H;
  float pe0[DIM], pe1[DIM];
  #pragma unroll
  for (int j = 0; j < DIM; ++j) {
    float s0 = b2[j], s1 = b2[j];
    #pragma unroll
    for (int i2 = 0; i2 < 32; ++i2) {
      unsigned w = w2h[j*32 + i2];
      s0 = dot2f(w, h0h[i2], s0);
      s1 = dot2f(w, h1h[i2], s1);
    }
    pe0[j] = s0; pe1[j] = s1;
  }

  unsigned st0[16], st1[16];
  #pragma unroll
  for (int j = 0; j < 16; ++j) {
    st0[j] = pkh(pe0[2*j], pe0[2*j+1]);
    st1[j] = pkh(pe1[2*j], pe1[2*j+1]);
  }
  uint4* d0 = (uint4*)(peh_ws + (size_t)ge0*32);
  uint4* d1 = (uint4*)(peh_ws + (size_t)ge1*32);
  #pragma unroll
  for (int i = 0; i < 4; ++i) { d0[i] = ((uint4*)st0)[i]; d1[i] = ((uint4*)st1)[i]; }
}

// ---------------- Pass B2: pe moments via MFMA (M = pe^T pe, spe = sum pe) ----------------
// A-operand == B-operand (symmetric): lane l holds pe[e0 + (l>>5)*8 + j][l&31], j=0..7.
// Any consistent k-permutation in the HW A/B layout cancels in A^T A.
__global__ __launch_bounds__(256) void k_pemom(
    const unsigned short* __restrict__ peh_ws, float* __restrict__ ws)
{
  const int b   = blockIdx.x >> 7;          // 128 blocks per batch
  const int blk = blockIdx.x & 127;
  const int wv  = threadIdx.x >> 6;
  const int l   = threadIdx.x & 63;
  const int c   = l & 31;
  const int h   = l >> 5;

  // each wave: 1024 elements = 64 tiles of 16
  const size_t ebase = (size_t)b*ENK + ((size_t)(blk*4 + wv))*1024;
  const unsigned short* pbase = peh_ws + ebase*32 + (size_t)h*8*32 + c;

  f16v acc;
  #pragma unroll
  for (int i = 0; i < 16; ++i) acc[i] = 0.f;
  float spe = 0.f;
  const unsigned ONE = pkh(1.f, 1.f);

  for (int t = 0; t < 64; ++t) {
    const unsigned short* p = pbase + (size_t)t*16*32;
    unsigned u0 = (unsigned)p[0*32]  | ((unsigned)p[1*32] << 16);
    unsigned u1 = (unsigned)p[2*32]  | ((unsigned)p[3*32] << 16);
    unsigned u2 = (unsigned)p[4*32]  | ((unsigned)p[5*32] << 16);
    unsigned u3 = (unsigned)p[6*32]  | ((unsigned)p[7*32] << 16);
    uint4 uu = make_uint4(u0, u1, u2, u3);
    h8v frag = __builtin_bit_cast(h8v, uu);
    acc = __builtin_amdgcn_mfma_f32_32x32x16_f16(frag, frag, acc, 0, 0, 0);
    spe = dot2f(u0, ONE, spe);
    spe = dot2f(u1, ONE, spe);
    spe = dot2f(u2, ONE, spe);
    spe = dot2f(u3, ONE, spe);
  }

  float* st2 = ws + WS_STATS2 + b*1056;
  spe += __shfl_down(spe, 32);
  if (l < 32) atomicAdd(st2 + c, spe);
  #pragma unroll
  for (int r = 0; r < 16; ++r) {
    int row = (r & 3) + 8*(r >> 2) + 4*h;
    atomicAdd(st2 + 32 + row*32 + c, acc[r]);
  }
}

// ---------------- Fold GN2 into Wa1, write half2-packed ----------------
__global__ __launch_bounds__(64) void k_fold2m(
    const float* __restrict__ wa1, const float* __restrict__ ba1,
    const float* __restrict__ gw2, const float* __restrict__ gb2,
    float* __restrict__ ws)
{
  int b = blockIdx.x, o = threadIdx.x;
  const float* st = ws + WS_STATS2 + b*1056;
  float w[32];
  const float4* wrow = (const float4*)wa1 + o*8;
  #pragma unroll
  for (int i = 0; i < 8; ++i) {
    float4 t = wrow[i];
    w[4*i] = t.x; w[4*i+1] = t.y; w[4*i+2] = t.z; w[4*i+3] = t.w;
  }
  float dot = 0.f;
  #pragma unroll
  for (int cc = 0; cc < 32; ++cc) dot = fmaf(w[cc], st[cc], dot);
  float quad = 0.f;
  #pragma unroll
  for (int rr = 0; rr < 32; ++rr) {
    const float* Mr = st + 32 + rr*32;
    float mr = 0.f;
    #pragma unroll
    for (int cc = 0; cc < 32; ++cc) mr = fmaf(Mr[cc], w[cc], mr);
    quad = fmaf(w[rr], mr, quad);
  }
  float bb = ba1[o];
  float sum = dot + EF*bb;
  float ssq = quad + 2.f*bb*dot + EF*bb*bb;
  #pragma unroll
  for (int m = 1; m < 16; m <<= 1) {
    sum += __shfl_xor(sum, m);
    ssq += __shfl_xor(ssq, m);
  }
  float mu  = sum / CNTG;
  float var = ssq / CNTG - mu*mu;
  float sc  = rsqrtf(var + 1e-5f) * gw2[o];
  unsigned* dst = (unsigned*)ws + WS_WA1H + (b*64 + o)*16;
  #pragma unroll
  for (int i2 = 0; i2 < 16; ++i2) dst[i2] = pkh(w[2*i2]*sc, w[2*i2+1]*sc);
  (ws + WS_BA1F)[b*64 + o] = (bb - mu)*sc + gb2[o];
}

// ---------------- Pass C: h2, logits, masked softmax, output ----------------
__global__ __launch_bounds__(256) void k_out(
    const unsigned short* __restrict__ peh_ws, const int* __restrict__ mask,
    const float* __restrict__ ba2,
    const float* __restrict__ ws, float* __restrict__ out)
{
  const int b = blockIdx.x >> 11;                // 2048 blocks per batch (uniform!)
  const int e = blockIdx.x*256 + threadIdx.x;
  const int n = (e & (ENK - 1)) >> 4;
  const int k = threadIdx.x & 15;

  unsigned peh[16];
  const uint4* src = (const uint4*)(peh_ws + (size_t)e*32);
  #pragma unroll
  for (int i = 0; i < 4; ++i) ((uint4*)peh)[i] = src[i];

  const unsigned* wa1h = (const unsigned*)ws + WS_WA1H + b*1024;
  const float*    ba1f = ws + WS_BA1F + b*64;
  const unsigned* wa2h = (const unsigned*)ws + WS_WA2H;

  unsigned h2h[32];
  #pragma unroll
  for (int oc = 0; oc < 4; ++oc) {
    float h2c[16];
    #pragma unroll
    for (int oo = 0; oo < 16; ++oo) {
      int o = oc*16 + oo;
      float acc = ba1f[o];
      #pragma unroll
      for (int i = 0; i < 16; ++i) acc = dot2f(wa1h[o*16 + i], peh[i], acc);
      h2c[oo] = fmaxf(acc, 0.f);
    }
    #pragma unroll
    for (int p = 0; p < 8; ++p) h2h[oc*8 + p] = pkh(h2c[2*p], h2c[2*p+1]);
  }

  float lg[DIM];
  #pragma unroll
  for (int j = 0; j < DIM; ++j) {
    float acc = ba2[j];
    #pragma unroll
    for (int i2 = 0; i2 < 32; ++i2) acc = dot2f(wa2h[j*32 + i2], h2h[i2], acc);
    lg[j] = acc;
  }

  const bool valid = mask[e] != 0;
  float* outb = out + b*(DIM*NN);

  #pragma unroll
  for (int j = 0; j < DIM; ++j) {
    float v = valid ? lg[j] : NEG_HUGE;
    float m = v;
    m = fmaxf(m, __shfl_xor(m, 1));
    m = fmaxf(m, __shfl_xor(m, 2));
    m = fmaxf(m, __shfl_xor(m, 4));
    m = fmaxf(m, __shfl_xor(m, 8));
    float p = __expf(v - m);
    float s = p;
    s += __shfl_xor(s, 1);
    s += __shfl_xor(s, 2);
    s += __shfl_xor(s, 4);
    s += __shfl_xor(s, 8);
    h2v hp = __builtin_bit_cast(h2v, peh[j >> 1]);
    float pej = (float)hp[j & 1];
    float cc = pej * p;
    cc += __shfl_xor(cc, 1);
    cc += __shfl_xor(cc, 2);
    cc += __shfl_xor(cc, 4);
    cc += __shfl_xor(cc, 8);
    if (k == 0) outb[j*NN + n] = cc / s;
  }
}

extern "C" void kernel_launch(void* const* d_in, const int* in_sizes, int n_in,
                              void* d_out, int out_size, void* d_ws, size_t ws_size,
                              hipStream_t stream) {
  (void)in_sizes; (void)n_in; (void)out_size; (void)ws_size;
  const float* q_xyzs   = (const float*)d_in[0];
  const float* k_xyzs   = (const float*)d_in[1];
  const int*   knn_idx  = (const int*)d_in[2];
  const int*   mask     = (const int*)d_in[3];
  const float* pre_w1   = (const float*)d_in[4];
  const float* pre_b1   = (const float*)d_in[5];
  const float* pre_gn_w = (const float*)d_in[6];
  const float* pre_gn_b = (const float*)d_in[7];
  const float* pre_w2   = (const float*)d_in[8];
  const float* pre_b2   = (const float*)d_in[9];
  const float* attn_w1  = (const float*)d_in[10];
  const float* attn_b1  = (const float*)d_in[11];
  const float* attn_gn_w= (const float*)d_in[12];
  const float* attn_gn_b= (const float*)d_in[13];
  const float* attn_w2  = (const float*)d_in[14];
  const float* attn_b2  = (const float*)d_in[15];
  float* ws  = (float*)d_ws;
  float* out = (float*)d_out;
  unsigned short* peh_ws = (unsigned short*)((char*)d_ws + PE_BYTE_OFF);

  hipMemsetAsync(ws, 0, (64 + 4*1056)*sizeof(float), stream);
  k_packw <<<dim3(1),        64, 0, stream>>>(pre_w2, attn_w2, (unsigned*)ws);
  k_lpmom <<<dim3(NB*256),  256, 0, stream>>>(q_xyzs, k_xyzs, knn_idx, ws);
  k_fold1 <<<dim3(NB),       64, 0, stream>>>(pre_w1, pre_b1, pre_gn_w, pre_gn_b, ws);
  k_pe    <<<dim3(NB*1024), 256, 0, stream>>>(q_xyzs, k_xyzs, knn_idx, pre_b2, ws, peh_ws);
  k_pemom <<<dim3(NB*128),  256, 0, stream>>>(peh_ws, ws);
  k_fold2m<<<dim3(NB),       64, 0, stream>>>(attn_w1, attn_b1, attn_gn_w, attn_gn_b, ws);
  k_out   <<<dim3(NB*2048), 256, 0, stream>>>(peh_ws, mask, attn_b2, ws, out);
}

// Round 5
// 257.756 us; speedup vs baseline: 6.1028x; 1.4738x over previous
//
#include <hip/hip_runtime.h>
#include <hip/hip_bf16.h>
#include <math.h>

#define NB 4
#define NN 32768
#define MM 32768
#define KK 16
#define HID 64
#define DIM 32
#define ENK (NN*KK)              // 524288 elements per batch (2^19)
#define EF  524288.0f
#define CNTG (16.0f*EF)
#define NEG_HUGE (-3.4028234663852886e38f)

// ---- workspace u32/float offsets (small region) ----
#define WS_STATS1 0        // [4][16]  : slp[4], M10[10], pad
#define WS_STATS2 64       // [4][1056]: spe[32], Mpe[32*32]
#define WS_W1F    4288     // [4][64][4] f32 folded pre_w1
#define WS_B1F    5312     // [4][64] f32
#define WS_WA1H   5568     // [4][64][16] u32 (half2-packed folded attn_w1)
#define WS_BA1F   9664     // [4][64] f32
#define WS_W2H    9920     // [32][32] u32 (half2-packed pre_w2)
#define WS_WA2H   10944    // [32][32] u32 (half2-packed attn_w2)
// ends 11968 floats = 47872 B < 65536
#define PE_BYTE_OFF 65536ull

typedef _Float16 h2v __attribute__((ext_vector_type(2)));
typedef _Float16 h8v __attribute__((ext_vector_type(8)));
typedef float f16v __attribute__((ext_vector_type(16)));

#if defined(__has_builtin)
#if __has_builtin(__builtin_amdgcn_fdot2)
#define USE_FDOT2 1
#endif
#endif
#ifndef USE_FDOT2
#define USE_FDOT2 0
#endif

__device__ __forceinline__ float dot2f(unsigned w, unsigned x, float acc) {
#if USE_FDOT2
  return __builtin_amdgcn_fdot2(__builtin_bit_cast(h2v, w),
                                __builtin_bit_cast(h2v, x), acc, false);
#else
  h2v a = __builtin_bit_cast(h2v, w);
  h2v b = __builtin_bit_cast(h2v, x);
  acc = fmaf((float)a[0], (float)b[0], acc);
  return fmaf((float)a[1], (float)b[1], acc);
#endif
}

__device__ __forceinline__ unsigned pkh(float a, float b) {
  return __builtin_bit_cast(unsigned, __builtin_amdgcn_cvt_pkrtz(a, b));
}

__device__ __forceinline__ f16v mfma16(uint4 a, uint4 b, f16v c) {
  return __builtin_amdgcn_mfma_f32_32x32x16_f16(
      __builtin_bit_cast(h8v, a), __builtin_bit_cast(h8v, b), c, 0, 0, 0);
}

template<int NV>
__device__ __forceinline__ void block_reduce_atomic(float* v, float* dst) {
  #pragma unroll
  for (int i = 0; i < NV; ++i) {
    float x = v[i];
    x += __shfl_down(x, 32);
    x += __shfl_down(x, 16);
    x += __shfl_down(x, 8);
    x += __shfl_down(x, 4);
    x += __shfl_down(x, 2);
    x += __shfl_down(x, 1);
    v[i] = x;
  }
  __shared__ float red[4][NV];
  const int lane = threadIdx.x & 63;
  const int wv = threadIdx.x >> 6;
  if (lane == 0) {
    #pragma unroll
    for (int i = 0; i < NV; ++i) red[wv][i] = v[i];
  }
  __syncthreads();
  if (threadIdx.x < NV) {
    float t = red[0][threadIdx.x] + red[1][threadIdx.x] +
              red[2][threadIdx.x] + red[3][threadIdx.x];
    atomicAdd(dst + threadIdx.x, t);
  }
}

__device__ __forceinline__ void compute_lp(const float* __restrict__ qb,
                                           const float* __restrict__ kb,
                                           int n, int idx,
                                           float& lp0, float& lp1, float& lp2, float& lp3) {
  float dx = kb[idx]        - qb[n];
  float dy = kb[MM + idx]   - qb[NN + n];
  float dz = kb[2*MM + idx] - qb[2*NN + n];
  float dist = sqrtf(fmaf(dx, dx, fmaf(dy, dy, dz*dz)));
  float inv = 1.0f / fmaxf(dist, 1e-12f);
  lp0 = dx * inv; lp1 = dy * inv; lp2 = dz * inv; lp3 = dist;
}

// ---------------- Pass A: lp moments ----------------
__global__ __launch_bounds__(256) void k_lpmom(
    const float* __restrict__ q_xyzs, const float* __restrict__ k_xyzs,
    const int* __restrict__ knn_idx, float* __restrict__ ws)
{
  const int b   = blockIdx.x >> 8;
  const int blk = blockIdx.x & 255;
  const float* qb = q_xyzs + b*3*NN;
  const float* kb = k_xyzs + b*3*MM;
  const int* idxb = knn_idx + b*ENK;

  float a[14];
  #pragma unroll
  for (int i = 0; i < 14; ++i) a[i] = 0.f;

  for (int it = 0; it < 8; ++it) {
    int el = (blk*8 + it)*256 + threadIdx.x;
    int n = el >> 4;
    int idx = idxb[el];
    float lp0, lp1, lp2, lp3;
    compute_lp(qb, kb, n, idx, lp0, lp1, lp2, lp3);
    a[0] += lp0; a[1] += lp1; a[2] += lp2; a[3] += lp3;
    a[4] = fmaf(lp0, lp0, a[4]);  a[5] = fmaf(lp0, lp1, a[5]);
    a[6] = fmaf(lp0, lp2, a[6]);  a[7] = fmaf(lp0, lp3, a[7]);
    a[8] = fmaf(lp1, lp1, a[8]);  a[9] = fmaf(lp1, lp2, a[9]);
    a[10] = fmaf(lp1, lp3, a[10]); a[11] = fmaf(lp2, lp2, a[11]);
    a[12] = fmaf(lp2, lp3, a[12]); a[13] = fmaf(lp3, lp3, a[13]);
  }
  block_reduce_atomic<14>(a, ws + WS_STATS1 + b*16);
}

// ---------------- Fold GN1 into W1 ----------------
__global__ __launch_bounds__(64) void k_fold1(
    const float* __restrict__ w1, const float* __restrict__ b1,
    const float* __restrict__ gw, const float* __restrict__ gb,
    float* __restrict__ ws)
{
  int b = blockIdx.x, o = threadIdx.x;
  const float* st = ws + WS_STATS1 + b*16;
  float4 w = ((const float4*)w1)[o];
  float bb = b1[o];
  float dot = w.x*st[0] + w.y*st[1] + w.z*st[2] + w.w*st[3];
  float quad = w.x*w.x*st[4] + w.y*w.y*st[8] + w.z*w.z*st[11] + w.w*w.w*st[13]
    + 2.f*(w.x*w.y*st[5] + w.x*w.z*st[6] + w.x*w.w*st[7]
         + w.y*w.z*st[9] + w.y*w.w*st[10] + w.z*w.w*st[12]);
  float sum = dot + EF*bb;
  float ssq = quad + 2.f*bb*dot + EF*bb*bb;
  #pragma unroll
  for (int m = 1; m < 16; m <<= 1) {
    sum += __shfl_xor(sum, m);
    ssq += __shfl_xor(ssq, m);
  }
  float mu  = sum / CNTG;
  float var = ssq / CNTG - mu*mu;
  float sc  = rsqrtf(var + 1e-5f) * gw[o];
  ((float4*)(ws + WS_W1F))[b*64 + o] = make_float4(w.x*sc, w.y*sc, w.z*sc, w.w*sc);
  (ws + WS_B1F)[b*64 + o] = (bb - mu)*sc + gb[o];
}

// ---------------- pack batch-independent weights to half2 ----------------
__global__ __launch_bounds__(64) void k_packw(
    const float* __restrict__ w2, const float* __restrict__ wa2,
    unsigned* __restrict__ wsu)
{
  int t = threadIdx.x;
  if (t < 32) {
    const float* src = w2 + t*64;
    unsigned* dst = wsu + WS_W2H + t*32;
    #pragma unroll
    for (int i = 0; i < 32; ++i) dst[i] = pkh(src[2*i], src[2*i+1]);
  } else {
    int j = t - 32;
    const float* src = wa2 + j*64;
    unsigned* dst = wsu + WS_WA2H + j*32;
    #pragma unroll
    for (int i = 0; i < 32; ++i) dst[i] = pkh(src[2*i], src[2*i+1]);
  }
}

// ---------------- Pass B: compute pe, store f16 (2 elements/thread) ----------------
__global__ __launch_bounds__(256) void k_pe(
    const float* __restrict__ q_xyzs, const float* __restrict__ k_xyzs,
    const int* __restrict__ knn_idx, const float* __restrict__ b2,
    const float* __restrict__ ws, unsigned short* __restrict__ peh_ws)
{
  const int b = blockIdx.x >> 10;                 // 1024 blocks per batch (uniform!)
  const int ge0 = blockIdx.x*512 + threadIdx.x;
  const int ge1 = ge0 + 256;
  const float* qb = q_xyzs + b*3*NN;
  const float* kb = k_xyzs + b*3*MM;

  int n0 = (ge0 & (ENK-1)) >> 4;
  int n1 = (ge1 & (ENK-1)) >> 4;
  int i0 = knn_idx[ge0];
  int i1 = knn_idx[ge1];
  float a0,a1,a2,a3, c0,c1,c2,c3;
  compute_lp(qb, kb, n0, i0, a0,a1,a2,a3);
  compute_lp(qb, kb, n1, i1, c0,c1,c2,c3);

  const float4* w1f = (const float4*)(ws + WS_W1F) + b*64;   // SGPR-based
  const float*  b1f = ws + WS_B1F + b*64;

  unsigned h0h[32], h1h[32];
  #pragma unroll
  for (int o2 = 0; o2 < 32; ++o2) {
    float4 wA = w1f[2*o2];   float bA = b1f[2*o2];
    float4 wB = w1f[2*o2+1]; float bB = b1f[2*o2+1];
    float xA0 = fmaxf(fmaf(wA.x, a0, fmaf(wA.y, a1, fmaf(wA.z, a2, fmaf(wA.w, a3, bA)))), 0.f);
    float xB0 = fmaxf(fmaf(wB.x, a0, fmaf(wB.y, a1, fmaf(wB.z, a2, fmaf(wB.w, a3, bB)))), 0.f);
    float xA1 = fmaxf(fmaf(wA.x, c0, fmaf(wA.y, c1, fmaf(wA.z, c2, fmaf(wA.w, c3, bA)))), 0.f);
    float xB1 = fmaxf(fmaf(wB.x, c0, fmaf(wB.y, c1, fmaf(wB.z, c2, fmaf(wB.w, c3, bB)))), 0.f);
    h0h[o2] = pkh(xA0, xB0);
    h1h[o2] = pkh(xA1, xB1);
  }

  const unsigned* w2h = (const unsigned*)ws + WS_W2H;
  float pe0[DIM], pe1[DIM];
  #pragma unroll
  for (int j = 0; j < DIM; ++j) {
    float s0 = b2[j], s1 = b2[j];
    #pragma unroll
    for (int i2 = 0; i2 < 32; ++i2) {
      unsigned w = w2h[j*32 + i2];
      s0 = dot2f(w, h0h[i2], s0);
      s1 = dot2f(w, h1h[i2], s1);
    }
    pe0[j] = s0; pe1[j] = s1;
  }

  unsigned st0[16], st1[16];
  #pragma unroll
  for (int j = 0; j < 16; ++j) {
    st0[j] = pkh(pe0[2*j], pe0[2*j+1]);
    st1[j] = pkh(pe1[2*j], pe1[2*j+1]);
  }
  uint4* d0 = (uint4*)(peh_ws + (size_t)ge0*32);
  uint4* d1 = (uint4*)(peh_ws + (size_t)ge1*32);
  #pragma unroll
  for (int i = 0; i < 4; ++i) { d0[i] = ((uint4*)st0)[i]; d1[i] = ((uint4*)st1)[i]; }
}

// ---------------- Pass B2: pe moments via MFMA (M = pe^T pe, spe = sum pe) ----------------
__global__ __launch_bounds__(256) void k_pemom(
    const unsigned short* __restrict__ peh_ws, float* __restrict__ ws)
{
  const int b   = blockIdx.x >> 7;          // 128 blocks per batch
  const int blk = blockIdx.x & 127;
  const int wv  = threadIdx.x >> 6;
  const int l   = threadIdx.x & 63;
  const int c   = l & 31;
  const int h   = l >> 5;

  const size_t ebase = (size_t)b*ENK + ((size_t)(blk*4 + wv))*1024;
  const unsigned short* pbase = peh_ws + ebase*32 + (size_t)h*8*32 + c;

  f16v acc;
  #pragma unroll
  for (int i = 0; i < 16; ++i) acc[i] = 0.f;
  float spe = 0.f;
  const unsigned ONE = pkh(1.f, 1.f);

  for (int t = 0; t < 64; ++t) {
    const unsigned short* p = pbase + (size_t)t*16*32;
    unsigned u0 = (unsigned)p[0*32]  | ((unsigned)p[1*32] << 16);
    unsigned u1 = (unsigned)p[2*32]  | ((unsigned)p[3*32] << 16);
    unsigned u2 = (unsigned)p[4*32]  | ((unsigned)p[5*32] << 16);
    unsigned u3 = (unsigned)p[6*32]  | ((unsigned)p[7*32] << 16);
    uint4 uu = make_uint4(u0, u1, u2, u3);
    h8v frag = __builtin_bit_cast(h8v, uu);
    acc = __builtin_amdgcn_mfma_f32_32x32x16_f16(frag, frag, acc, 0, 0, 0);
    spe = dot2f(u0, ONE, spe);
    spe = dot2f(u1, ONE, spe);
    spe = dot2f(u2, ONE, spe);
    spe = dot2f(u3, ONE, spe);
  }

  float* st2 = ws + WS_STATS2 + b*1056;
  spe += __shfl_down(spe, 32);
  if (l < 32) atomicAdd(st2 + c, spe);
  #pragma unroll
  for (int r = 0; r < 16; ++r) {
    int row = (r & 3) + 8*(r >> 2) + 4*h;
    atomicAdd(st2 + 32 + row*32 + c, acc[r]);
  }
}

// ---------------- Fold GN2 into Wa1, write half2-packed ----------------
__global__ __launch_bounds__(64) void k_fold2m(
    const float* __restrict__ wa1, const float* __restrict__ ba1,
    const float* __restrict__ gw2, const float* __restrict__ gb2,
    float* __restrict__ ws)
{
  int b = blockIdx.x, o = threadIdx.x;
  const float* st = ws + WS_STATS2 + b*1056;
  float w[32];
  const float4* wrow = (const float4*)wa1 + o*8;
  #pragma unroll
  for (int i = 0; i < 8; ++i) {
    float4 t = wrow[i];
    w[4*i] = t.x; w[4*i+1] = t.y; w[4*i+2] = t.z; w[4*i+3] = t.w;
  }
  float dot = 0.f;
  #pragma unroll
  for (int cc = 0; cc < 32; ++cc) dot = fmaf(w[cc], st[cc], dot);
  float quad = 0.f;
  #pragma unroll
  for (int rr = 0; rr < 32; ++rr) {
    const float* Mr = st + 32 + rr*32;
    float mr = 0.f;
    #pragma unroll
    for (int cc = 0; cc < 32; ++cc) mr = fmaf(Mr[cc], w[cc], mr);
    quad = fmaf(w[rr], mr, quad);
  }
  float bb = ba1[o];
  float sum = dot + EF*bb;
  float ssq = quad + 2.f*bb*dot + EF*bb*bb;
  #pragma unroll
  for (int m = 1; m < 16; m <<= 1) {
    sum += __shfl_xor(sum, m);
    ssq += __shfl_xor(ssq, m);
  }
  float mu  = sum / CNTG;
  float var = ssq / CNTG - mu*mu;
  float sc  = rsqrtf(var + 1e-5f) * gw2[o];
  unsigned* dst = (unsigned*)ws + WS_WA1H + (b*64 + o)*16;
  #pragma unroll
  for (int i2 = 0; i2 < 16; ++i2) dst[i2] = pkh(w[2*i2]*sc, w[2*i2+1]*sc);
  (ws + WS_BA1F)[b*64 + o] = (bb - mu)*sc + gb2[o];
}

// ---------------- Pass C (MFMA): h2, logits, masked softmax, output ----------------
// Per 32-element tile:
//   GEMM1: D1[o][e] = Wa1f(A) x pe(B), o-tiles t=0,1, K=32 (2 chunks).
//   half-exchange D1 (pack f16 pairs, shfl_xor 32, h-select) -> A-frags of h2^T.
//   GEMM2 (transposed): D2[e][j] = h2ex(A) x Wa2(B), K=64 (4 chunks).
//   Softmax over e (rows; serial per-lane + one shfl_xor(32)), weighted pe sum.
__global__ __launch_bounds__(256) void k_out(
    const unsigned short* __restrict__ peh_ws, const int* __restrict__ mask,
    const float* __restrict__ ba2,
    const float* __restrict__ ws, float* __restrict__ out)
{
  const int b  = blockIdx.x >> 8;           // 256 blocks per batch (uniform)
  const int l  = threadIdx.x & 63;
  const int wv = threadIdx.x >> 6;
  const int c  = l & 31;
  const int h  = l >> 5;

  // A-frags for GEMM1: Wa1f[m = c+32t][ch = kc*16 + h*8 + jj]
  const unsigned* wa1h = (const unsigned*)ws + WS_WA1H + b*1024;
  const unsigned* wa2h = (const unsigned*)ws + WS_WA2H;
  uint4 A1[2][2], A2w[4];
  #pragma unroll
  for (int t = 0; t < 2; ++t)
    #pragma unroll
    for (int kc = 0; kc < 2; ++kc)
      A1[t][kc] = *(const uint4*)(wa1h + (c + 32*t)*16 + kc*8 + h*4);
  // B-frags for GEMM2: Wa2[n = c][o = kc2*16 + h*8 + jj]
  #pragma unroll
  for (int kc2 = 0; kc2 < 4; ++kc2)
    A2w[kc2] = *(const uint4*)(wa2h + c*32 + kc2*8 + h*4);

  // biases: acc1 rows o = (r&3)+8(r>>2)+4h+32t ; acc2 cols j = c
  const float* ba1f = ws + WS_BA1F + b*64;
  float bias1[2][16];
  #pragma unroll
  for (int t = 0; t < 2; ++t)
    #pragma unroll
    for (int r = 0; r < 16; ++r)
      bias1[t][r] = ba1f[(r&3) + 8*(r>>2) + 4*h + 32*t];
  const float ba2j = ba2[c];

  const int e0w = blockIdx.x*2048 + wv*512;
  float* outb = out + b*(DIM*NN) + c*NN;

  #pragma unroll 1
  for (int tt = 0; tt < 16; ++tt) {
    const int e0 = e0w + tt*32;
    // pe B-frags: pe[ch = kc*16 + h*8 + jj][e = e0 + c]
    const unsigned short* peb = peh_ws + (size_t)(e0 + c)*32 + h*8;
    uint4 peB0 = *(const uint4*)peb;
    uint4 peB1 = *(const uint4*)(peb + 16);

    // GEMM1
    f16v acc1a, acc1b;
    #pragma unroll
    for (int r = 0; r < 16; ++r) { acc1a[r] = bias1[0][r]; acc1b[r] = bias1[1][r]; }
    acc1a = mfma16(A1[0][0], peB0, acc1a);
    acc1a = mfma16(A1[0][1], peB1, acc1a);
    acc1b = mfma16(A1[1][0], peB0, acc1b);
    acc1b = mfma16(A1[1][1], peB1, acc1b);

    // relu + pack adjacent-row pairs: u[t][p] = rows (O, O+1), O = (2p&3)+8(p>>1)+4h+32t
    unsigned u0[8], u1[8], x0[8], x1[8];
    #pragma unroll
    for (int p = 0; p < 8; ++p) {
      u0[p] = pkh(fmaxf(acc1a[2*p], 0.f), fmaxf(acc1a[2*p+1], 0.f));
      u1[p] = pkh(fmaxf(acc1b[2*p], 0.f), fmaxf(acc1b[2*p+1], 0.f));
    }
    #pragma unroll
    for (int p = 0; p < 8; ++p) {
      x0[p] = __shfl_xor(u0[p], 32);
      x1[p] = __shfl_xor(u1[p], 32);
    }

    // GEMM2 (transposed): acc2[e-rows][j=c]
    f16v acc2;
    #pragma unroll
    for (int r = 0; r < 16; ++r) acc2[r] = ba2j;
    #pragma unroll
    for (int kc2 = 0; kc2 < 4; ++kc2) {
      const int c1 = kc2 & 1;
      uint4 f;
      if ((kc2 >> 1) == 0) {
        f.x = h ? x0[4*c1+2] : u0[4*c1+0];
        f.y = h ? x0[4*c1+3] : u0[4*c1+1];
        f.z = h ? u0[4*c1+2] : x0[4*c1+0];
        f.w = h ? u0[4*c1+3] : x0[4*c1+1];
      } else {
        f.x = h ? x1[4*c1+2] : u1[4*c1+0];
        f.y = h ? x1[4*c1+3] : u1[4*c1+1];
        f.z = h ? u1[4*c1+2] : x1[4*c1+0];
        f.w = h ? u1[4*c1+3] : x1[4*c1+1];
      }
      acc2 = mfma16(f, A2w[kc2], acc2);
    }

    // masks (int2 per adjacent row pair) + pe[j=c][e-row] reload
    float v[16], pe_r[16];
    #pragma unroll
    for (int p = 0; p < 8; ++p) {
      int ebase = (2*p & 3) + 8*(p >> 1) + 4*h;
      int2 mm = *(const int2*)(mask + e0 + ebase);
      v[2*p]   = mm.x ? acc2[2*p]   : NEG_HUGE;
      v[2*p+1] = mm.y ? acc2[2*p+1] : NEG_HUGE;
      pe_r[2*p]   = (float)*(const _Float16*)(peh_ws + (size_t)(e0 + ebase)*32 + c);
      pe_r[2*p+1] = (float)*(const _Float16*)(peh_ws + (size_t)(e0 + ebase + 1)*32 + c);
    }

    // group A = regs 0..7 (e-rows 0..15), group B = regs 8..15 (e-rows 16..31)
    float mA = v[0], mB = v[8];
    #pragma unroll
    for (int r = 1; r < 8; ++r) { mA = fmaxf(mA, v[r]); mB = fmaxf(mB, v[r+8]); }
    mA = fmaxf(mA, __shfl_xor(mA, 32));
    mB = fmaxf(mB, __shfl_xor(mB, 32));

    float sA = 0.f, wA = 0.f, sB = 0.f, wB = 0.f;
    #pragma unroll
    for (int r = 0; r < 8; ++r) {
      float pa = __expf(v[r]   - mA);
      float pb = __expf(v[r+8] - mB);
      sA += pa; wA = fmaf(pa, pe_r[r],   wA);
      sB += pb; wB = fmaf(pb, pe_r[r+8], wB);
    }
    sA += __shfl_xor(sA, 32); wA += __shfl_xor(wA, 32);
    sB += __shfl_xor(sB, 32); wB += __shfl_xor(wB, 32);

    float num = h ? wB : wA;
    float den = h ? sB : sA;
    int n = ((e0 & (ENK - 1)) >> 4) + h;
    outb[n] = __fdividef(num, den);
  }
}

extern "C" void kernel_launch(void* const* d_in, const int* in_sizes, int n_in,
                              void* d_out, int out_size, void* d_ws, size_t ws_size,
                              hipStream_t stream) {
  (void)in_sizes; (void)n_in; (void)out_size; (void)ws_size;
  const float* q_xyzs   = (const float*)d_in[0];
  const float* k_xyzs   = (const float*)d_in[1];
  const int*   knn_idx  = (const int*)d_in[2];
  const int*   mask     = (const int*)d_in[3];
  const float* pre_w1   = (const float*)d_in[4];
  const float* pre_b1   = (const float*)d_in[5];
  const float* pre_gn_w = (const float*)d_in[6];
  const float* pre_gn_b = (const float*)d_in[7];
  const float* pre_w2   = (const float*)d_in[8];
  const float* pre_b2   = (const float*)d_in[9];
  const float* attn_w1  = (const float*)d_in[10];
  const float* attn_b1  = (const float*)d_in[11];
  const float* attn_gn_w= (const float*)d_in[12];
  const float* attn_gn_b= (const float*)d_in[13];
  const float* attn_w2  = (const float*)d_in[14];
  const float* attn_b2  = (const float*)d_in[15];
  float* ws  = (float*)d_ws;
  float* out = (float*)d_out;
  unsigned short* peh_ws = (unsigned short*)((char*)d_ws + PE_BYTE_OFF);

  hipMemsetAsync(ws, 0, (64 + 4*1056)*sizeof(float), stream);
  k_packw <<<dim3(1),        64, 0, stream>>>(pre_w2, attn_w2, (unsigned*)ws);
  k_lpmom <<<dim3(NB*256),  256, 0, stream>>>(q_xyzs, k_xyzs, knn_idx, ws);
  k_fold1 <<<dim3(NB),       64, 0, stream>>>(pre_w1, pre_b1, pre_gn_w, pre_gn_b, ws);
  k_pe    <<<dim3(NB*1024), 256, 0, stream>>>(q_xyzs, k_xyzs, knn_idx, pre_b2, ws, peh_ws);
  k_pemom <<<dim3(NB*128),  256, 0, stream>>>(peh_ws, ws);
  k_fold2m<<<dim3(NB),       64, 0, stream>>>(attn_w1, attn_b1, attn_gn_w, attn_gn_b, ws);
  k_out   <<<dim3(NB*256),  256, 0, stream>>>(peh_ws, mask, attn_b2, ws, out);
}

// Round 6
// 216.942 us; speedup vs baseline: 7.2509x; 1.1881x over previous
//
#include <hip/hip_runtime.h>
#include <hip/hip_bf16.h>
#include <math.h>

#define NB 4
#define NN 32768
#define MM 32768
#define KK 16
#define HID 64
#define DIM 32
#define ENK (NN*KK)              // 524288 elements per batch (2^19)
#define EF  524288.0f
#define CNTG (16.0f*EF)
#define NEG_HUGE (-3.4028234663852886e38f)

// ---- workspace u32/float offsets (small region) ----
#define WS_STATS1 0        // [4][16]  : slp[4], M10[10], pad
#define WS_STATS2 64       // [4][1056]: spe[32], Mpe[32*32]
#define WS_W1F    4288     // [4][64][4] f32 folded pre_w1 (legacy, unused)
#define WS_B1F    5312     // [4][64] f32
#define WS_WA1H   5568     // [4][64][16] u32 (half2-packed folded attn_w1)
#define WS_BA1F   9664     // [4][64] f32
#define WS_W2H    9920     // [32][32] u32 (half2-packed pre_w2)
#define WS_WA2H   10944    // [32][32] u32 (half2-packed attn_w2)
#define WS_W1H    11968    // [4][64][2] u32 (half2-packed folded pre_w1)
// ends 12480 floats = 49920 B < 65536
#define PE_BYTE_OFF 65536ull

typedef _Float16 h2v __attribute__((ext_vector_type(2)));
typedef _Float16 h8v __attribute__((ext_vector_type(8)));
typedef float f16v __attribute__((ext_vector_type(16)));

#if defined(__has_builtin)
#if __has_builtin(__builtin_amdgcn_fdot2)
#define USE_FDOT2 1
#endif
#endif
#ifndef USE_FDOT2
#define USE_FDOT2 0
#endif

__device__ __forceinline__ float dot2f(unsigned w, unsigned x, float acc) {
#if USE_FDOT2
  return __builtin_amdgcn_fdot2(__builtin_bit_cast(h2v, w),
                                __builtin_bit_cast(h2v, x), acc, false);
#else
  h2v a = __builtin_bit_cast(h2v, w);
  h2v b = __builtin_bit_cast(h2v, x);
  acc = fmaf((float)a[0], (float)b[0], acc);
  return fmaf((float)a[1], (float)b[1], acc);
#endif
}

__device__ __forceinline__ unsigned pkh(float a, float b) {
  return __builtin_bit_cast(unsigned, __builtin_amdgcn_cvt_pkrtz(a, b));
}

__device__ __forceinline__ f16v mfma16(uint4 a, uint4 b, f16v c) {
  return __builtin_amdgcn_mfma_f32_32x32x16_f16(
      __builtin_bit_cast(h8v, a), __builtin_bit_cast(h8v, b), c, 0, 0, 0);
}

template<int NV>
__device__ __forceinline__ void block_reduce_atomic(float* v, float* dst) {
  #pragma unroll
  for (int i = 0; i < NV; ++i) {
    float x = v[i];
    x += __shfl_down(x, 32);
    x += __shfl_down(x, 16);
    x += __shfl_down(x, 8);
    x += __shfl_down(x, 4);
    x += __shfl_down(x, 2);
    x += __shfl_down(x, 1);
    v[i] = x;
  }
  __shared__ float red[4][NV];
  const int lane = threadIdx.x & 63;
  const int wv = threadIdx.x >> 6;
  if (lane == 0) {
    #pragma unroll
    for (int i = 0; i < NV; ++i) red[wv][i] = v[i];
  }
  __syncthreads();
  if (threadIdx.x < NV) {
    float t = red[0][threadIdx.x] + red[1][threadIdx.x] +
              red[2][threadIdx.x] + red[3][threadIdx.x];
    atomicAdd(dst + threadIdx.x, t);
  }
}

__device__ __forceinline__ void compute_lp(const float* __restrict__ qb,
                                           const float* __restrict__ kb,
                                           int n, int idx,
                                           float& lp0, float& lp1, float& lp2, float& lp3) {
  float dx = kb[idx]        - qb[n];
  float dy = kb[MM + idx]   - qb[NN + n];
  float dz = kb[2*MM + idx] - qb[2*NN + n];
  float dist = sqrtf(fmaf(dx, dx, fmaf(dy, dy, dz*dz)));
  float inv = 1.0f / fmaxf(dist, 1e-12f);
  lp0 = dx * inv; lp1 = dy * inv; lp2 = dz * inv; lp3 = dist;
}

// ---------------- Pass A: lp moments ----------------
__global__ __launch_bounds__(256) void k_lpmom(
    const float* __restrict__ q_xyzs, const float* __restrict__ k_xyzs,
    const int* __restrict__ knn_idx, float* __restrict__ ws)
{
  const int b   = blockIdx.x >> 8;
  const int blk = blockIdx.x & 255;
  const float* qb = q_xyzs + b*3*NN;
  const float* kb = k_xyzs + b*3*MM;
  const int* idxb = knn_idx + b*ENK;

  float a[14];
  #pragma unroll
  for (int i = 0; i < 14; ++i) a[i] = 0.f;

  for (int it = 0; it < 8; ++it) {
    int el = (blk*8 + it)*256 + threadIdx.x;
    int n = el >> 4;
    int idx = idxb[el];
    float lp0, lp1, lp2, lp3;
    compute_lp(qb, kb, n, idx, lp0, lp1, lp2, lp3);
    a[0] += lp0; a[1] += lp1; a[2] += lp2; a[3] += lp3;
    a[4] = fmaf(lp0, lp0, a[4]);  a[5] = fmaf(lp0, lp1, a[5]);
    a[6] = fmaf(lp0, lp2, a[6]);  a[7] = fmaf(lp0, lp3, a[7]);
    a[8] = fmaf(lp1, lp1, a[8]);  a[9] = fmaf(lp1, lp2, a[9]);
    a[10] = fmaf(lp1, lp3, a[10]); a[11] = fmaf(lp2, lp2, a[11]);
    a[12] = fmaf(lp2, lp3, a[12]); a[13] = fmaf(lp3, lp3, a[13]);
  }
  block_reduce_atomic<14>(a, ws + WS_STATS1 + b*16);
}

// ---------------- Fold GN1 into W1 (writes half2-packed + f32 bias) ----------------
__global__ __launch_bounds__(64) void k_fold1(
    const float* __restrict__ w1, const float* __restrict__ b1,
    const float* __restrict__ gw, const float* __restrict__ gb,
    float* __restrict__ ws)
{
  int b = blockIdx.x, o = threadIdx.x;
  const float* st = ws + WS_STATS1 + b*16;
  float4 w = ((const float4*)w1)[o];
  float bb = b1[o];
  float dot = w.x*st[0] + w.y*st[1] + w.z*st[2] + w.w*st[3];
  float quad = w.x*w.x*st[4] + w.y*w.y*st[8] + w.z*w.z*st[11] + w.w*w.w*st[13]
    + 2.f*(w.x*w.y*st[5] + w.x*w.z*st[6] + w.x*w.w*st[7]
         + w.y*w.z*st[9] + w.y*w.w*st[10] + w.z*w.w*st[12]);
  float sum = dot + EF*bb;
  float ssq = quad + 2.f*bb*dot + EF*bb*bb;
  #pragma unroll
  for (int m = 1; m < 16; m <<= 1) {
    sum += __shfl_xor(sum, m);
    ssq += __shfl_xor(ssq, m);
  }
  float mu  = sum / CNTG;
  float var = ssq / CNTG - mu*mu;
  float sc  = rsqrtf(var + 1e-5f) * gw[o];
  unsigned* w1hd = (unsigned*)ws + WS_W1H + b*128;
  w1hd[o*2]   = pkh(w.x*sc, w.y*sc);
  w1hd[o*2+1] = pkh(w.z*sc, w.w*sc);
  (ws + WS_B1F)[b*64 + o] = (bb - mu)*sc + gb[o];
}

// ---------------- pack batch-independent weights to half2 ----------------
__global__ __launch_bounds__(64) void k_packw(
    const float* __restrict__ w2, const float* __restrict__ wa2,
    unsigned* __restrict__ wsu)
{
  int t = threadIdx.x;
  if (t < 32) {
    const float* src = w2 + t*64;
    unsigned* dst = wsu + WS_W2H + t*32;
    #pragma unroll
    for (int i = 0; i < 32; ++i) dst[i] = pkh(src[2*i], src[2*i+1]);
  } else {
    int j = t - 32;
    const float* src = wa2 + j*64;
    unsigned* dst = wsu + WS_WA2H + j*32;
    #pragma unroll
    for (int i = 0; i < 32; ++i) dst[i] = pkh(src[2*i], src[2*i+1]);
  }
}

// ---------------- Pass B (MFMA): gather -> h1 -> pe = W2 h1 + b2, store f16 ----------------
// Per 32-element tile: lane (c,h) owns element e0+c.
//   B-frag: h1[ch = kc*16 + h*8 + jj][e = e0+c] computed in-lane via f16 dot2.
//   A-frag: W2[row=c][ch] (validated layout). acc rows j=(r&3)+8(r>>2)+4h, col e.
//   pack + shfl_xor(32) exchange -> element-major, 2 uint4 stores per lane.
__global__ __launch_bounds__(256) void k_pe(
    const float* __restrict__ q_xyzs, const float* __restrict__ k_xyzs,
    const int* __restrict__ knn_idx, const float* __restrict__ b2,
    const float* __restrict__ ws, unsigned short* __restrict__ peh_ws)
{
  const int b  = blockIdx.x >> 8;           // 256 blocks per batch (uniform)
  const int l  = threadIdx.x & 63;
  const int wv = threadIdx.x >> 6;
  const int c  = l & 31;
  const int h  = l >> 5;
  const float* qb = q_xyzs + b*3*NN;
  const float* kb = k_xyzs + b*3*MM;

  // hoisted per-lane folded-W1 half2 weights + f32 bias (32 channels per lane)
  const unsigned* w1h = (const unsigned*)ws + WS_W1H + b*128;
  const float* b1f = ws + WS_B1F + b*64;
  unsigned w01[32], w23[32];
  float bch[32];
  #pragma unroll
  for (int kc = 0; kc < 4; ++kc)
    #pragma unroll
    for (int jj = 0; jj < 8; ++jj) {
      int ch = kc*16 + h*8 + jj;
      w01[kc*8+jj] = w1h[ch*2];
      w23[kc*8+jj] = w1h[ch*2+1];
      bch[kc*8+jj] = b1f[ch];
    }
  const unsigned* w2h = (const unsigned*)ws + WS_W2H;
  uint4 A2[4];
  #pragma unroll
  for (int kc = 0; kc < 4; ++kc)
    A2[kc] = *(const uint4*)(w2h + c*32 + kc*8 + h*4);
  float bias2[16];
  #pragma unroll
  for (int r = 0; r < 16; ++r) bias2[r] = b2[(r&3) + 8*(r>>2) + 4*h];

  const int e0w = blockIdx.x*2048 + wv*512;

  #pragma unroll 1
  for (int tt = 0; tt < 16; ++tt) {
    const int e = e0w + tt*32 + c;
    int n = (e & (ENK-1)) >> 4;
    int idx = knn_idx[e];
    float lp0, lp1, lp2, lp3;
    compute_lp(qb, kb, n, idx, lp0, lp1, lp2, lp3);
    unsigned lp01 = pkh(lp0, lp1), lp23 = pkh(lp2, lp3);

    uint4 Bf[4];
    #pragma unroll
    for (int kc = 0; kc < 4; ++kc) {
      unsigned bb[4];
      #pragma unroll
      for (int q = 0; q < 4; ++q) {
        int i0 = kc*8 + 2*q, i1 = i0 + 1;
        float xa = fmaxf(dot2f(w01[i0], lp01, dot2f(w23[i0], lp23, bch[i0])), 0.f);
        float xb = fmaxf(dot2f(w01[i1], lp01, dot2f(w23[i1], lp23, bch[i1])), 0.f);
        bb[q] = pkh(xa, xb);
      }
      Bf[kc] = make_uint4(bb[0], bb[1], bb[2], bb[3]);
    }

    f16v acc;
    #pragma unroll
    for (int r = 0; r < 16; ++r) acc[r] = bias2[r];
    #pragma unroll
    for (int kc = 0; kc < 4; ++kc) acc = mfma16(A2[kc], Bf[kc], acc);

    // pack row pairs, exchange halves, assemble element-major, store
    unsigned u[8], x[8];
    #pragma unroll
    for (int p = 0; p < 8; ++p) u[p] = pkh(acc[2*p], acc[2*p+1]);
    #pragma unroll
    for (int p = 0; p < 8; ++p) x[p] = __shfl_xor(u[p], 32);
    uint4 f0, f1;
    f0.x = h ? x[4] : u[0];  f0.y = h ? x[5] : u[1];
    f0.z = h ? u[4] : x[0];  f0.w = h ? u[5] : x[1];
    f1.x = h ? x[6] : u[2];  f1.y = h ? x[7] : u[3];
    f1.z = h ? u[6] : x[2];  f1.w = h ? u[7] : x[3];
    uint4* d = (uint4*)(peh_ws + (size_t)e*32 + h*16);
    d[0] = f0;
    d[1] = f1;
  }
}

// ---------------- Pass B2: pe moments via MFMA (M = pe^T pe, spe = sum pe) ----------------
__global__ __launch_bounds__(256) void k_pemom(
    const unsigned short* __restrict__ peh_ws, float* __restrict__ ws)
{
  const int b   = blockIdx.x >> 7;          // 128 blocks per batch
  const int blk = blockIdx.x & 127;
  const int wv  = threadIdx.x >> 6;
  const int l   = threadIdx.x & 63;
  const int c   = l & 31;
  const int h   = l >> 5;

  const size_t ebase = (size_t)b*ENK + ((size_t)(blk*4 + wv))*1024;
  const unsigned short* pbase = peh_ws + ebase*32 + (size_t)h*8*32 + c;

  f16v acc;
  #pragma unroll
  for (int i = 0; i < 16; ++i) acc[i] = 0.f;
  float spe = 0.f;
  const unsigned ONE = pkh(1.f, 1.f);

  for (int t = 0; t < 64; ++t) {
    const unsigned short* p = pbase + (size_t)t*16*32;
    unsigned u0 = (unsigned)p[0*32]  | ((unsigned)p[1*32] << 16);
    unsigned u1 = (unsigned)p[2*32]  | ((unsigned)p[3*32] << 16);
    unsigned u2 = (unsigned)p[4*32]  | ((unsigned)p[5*32] << 16);
    unsigned u3 = (unsigned)p[6*32]  | ((unsigned)p[7*32] << 16);
    uint4 uu = make_uint4(u0, u1, u2, u3);
    h8v frag = __builtin_bit_cast(h8v, uu);
    acc = __builtin_amdgcn_mfma_f32_32x32x16_f16(frag, frag, acc, 0, 0, 0);
    spe = dot2f(u0, ONE, spe);
    spe = dot2f(u1, ONE, spe);
    spe = dot2f(u2, ONE, spe);
    spe = dot2f(u3, ONE, spe);
  }

  float* st2 = ws + WS_STATS2 + b*1056;
  spe += __shfl_down(spe, 32);
  if (l < 32) atomicAdd(st2 + c, spe);
  #pragma unroll
  for (int r = 0; r < 16; ++r) {
    int row = (r & 3) + 8*(r >> 2) + 4*h;
    atomicAdd(st2 + 32 + row*32 + c, acc[r]);
  }
}

// ---------------- Fold GN2 into Wa1, write half2-packed ----------------
__global__ __launch_bounds__(64) void k_fold2m(
    const float* __restrict__ wa1, const float* __restrict__ ba1,
    const float* __restrict__ gw2, const float* __restrict__ gb2,
    float* __restrict__ ws)
{
  int b = blockIdx.x, o = threadIdx.x;
  const float* st = ws + WS_STATS2 + b*1056;
  float w[32];
  const float4* wrow = (const float4*)wa1 + o*8;
  #pragma unroll
  for (int i = 0; i < 8; ++i) {
    float4 t = wrow[i];
    w[4*i] = t.x; w[4*i+1] = t.y; w[4*i+2] = t.z; w[4*i+3] = t.w;
  }
  float dot = 0.f;
  #pragma unroll
  for (int cc = 0; cc < 32; ++cc) dot = fmaf(w[cc], st[cc], dot);
  float quad = 0.f;
  #pragma unroll
  for (int rr = 0; rr < 32; ++rr) {
    const float* Mr = st + 32 + rr*32;
    float mr = 0.f;
    #pragma unroll
    for (int cc = 0; cc < 32; ++cc) mr = fmaf(Mr[cc], w[cc], mr);
    quad = fmaf(w[rr], mr, quad);
  }
  float bb = ba1[o];
  float sum = dot + EF*bb;
  float ssq = quad + 2.f*bb*dot + EF*bb*bb;
  #pragma unroll
  for (int m = 1; m < 16; m <<= 1) {
    sum += __shfl_xor(sum, m);
    ssq += __shfl_xor(ssq, m);
  }
  float mu  = sum / CNTG;
  float var = ssq / CNTG - mu*mu;
  float sc  = rsqrtf(var + 1e-5f) * gw2[o];
  unsigned* dst = (unsigned*)ws + WS_WA1H + (b*64 + o)*16;
  #pragma unroll
  for (int i2 = 0; i2 < 16; ++i2) dst[i2] = pkh(w[2*i2]*sc, w[2*i2+1]*sc);
  (ws + WS_BA1F)[b*64 + o] = (bb - mu)*sc + gb2[o];
}

// ---------------- Pass C (MFMA): h2, logits, masked softmax, output ----------------
__global__ __launch_bounds__(256) void k_out(
    const unsigned short* __restrict__ peh_ws, const int* __restrict__ mask,
    const float* __restrict__ ba2,
    const float* __restrict__ ws, float* __restrict__ out)
{
  __shared__ float so[32][132];             // [c][128 n + pad] staged output tile
  const int b  = blockIdx.x >> 8;           // 256 blocks per batch (uniform)
  const int l  = threadIdx.x & 63;
  const int wv = threadIdx.x >> 6;
  const int c  = l & 31;
  const int h  = l >> 5;

  const unsigned* wa1h = (const unsigned*)ws + WS_WA1H + b*1024;
  const unsigned* wa2h = (const unsigned*)ws + WS_WA2H;
  uint4 A1[2][2], A2w[4];
  #pragma unroll
  for (int t = 0; t < 2; ++t)
    #pragma unroll
    for (int kc = 0; kc < 2; ++kc)
      A1[t][kc] = *(const uint4*)(wa1h + (c + 32*t)*16 + kc*8 + h*4);
  #pragma unroll
  for (int kc2 = 0; kc2 < 4; ++kc2)
    A2w[kc2] = *(const uint4*)(wa2h + c*32 + kc2*8 + h*4);

  const float* ba1f = ws + WS_BA1F + b*64;
  float bias1[2][16];
  #pragma unroll
  for (int t = 0; t < 2; ++t)
    #pragma unroll
    for (int r = 0; r < 16; ++r)
      bias1[t][r] = ba1f[(r&3) + 8*(r>>2) + 4*h + 32*t];
  const float ba2j = ba2[c];

  const int e0w = blockIdx.x*2048 + wv*512;

  #pragma unroll 1
  for (int tt = 0; tt < 16; ++tt) {
    const int e0 = e0w + tt*32;
    const unsigned short* peb = peh_ws + (size_t)(e0 + c)*32 + h*8;
    uint4 peB0 = *(const uint4*)peb;
    uint4 peB1 = *(const uint4*)(peb + 16);

    f16v acc1a, acc1b;
    #pragma unroll
    for (int r = 0; r < 16; ++r) { acc1a[r] = bias1[0][r]; acc1b[r] = bias1[1][r]; }
    acc1a = mfma16(A1[0][0], peB0, acc1a);
    acc1a = mfma16(A1[0][1], peB1, acc1a);
    acc1b = mfma16(A1[1][0], peB0, acc1b);
    acc1b = mfma16(A1[1][1], peB1, acc1b);

    unsigned u0[8], u1[8], x0[8], x1[8];
    #pragma unroll
    for (int p = 0; p < 8; ++p) {
      u0[p] = pkh(fmaxf(acc1a[2*p], 0.f), fmaxf(acc1a[2*p+1], 0.f));
      u1[p] = pkh(fmaxf(acc1b[2*p], 0.f), fmaxf(acc1b[2*p+1], 0.f));
    }
    #pragma unroll
    for (int p = 0; p < 8; ++p) {
      x0[p] = __shfl_xor(u0[p], 32);
      x1[p] = __shfl_xor(u1[p], 32);
    }

    f16v acc2;
    #pragma unroll
    for (int r = 0; r < 16; ++r) acc2[r] = ba2j;
    #pragma unroll
    for (int kc2 = 0; kc2 < 4; ++kc2) {
      const int c1 = kc2 & 1;
      uint4 f;
      if ((kc2 >> 1) == 0) {
        f.x = h ? x0[4*c1+2] : u0[4*c1+0];
        f.y = h ? x0[4*c1+3] : u0[4*c1+1];
        f.z = h ? u0[4*c1+2] : x0[4*c1+0];
        f.w = h ? u0[4*c1+3] : x0[4*c1+1];
      } else {
        f.x = h ? x1[4*c1+2] : u1[4*c1+0];
        f.y = h ? x1[4*c1+3] : u1[4*c1+1];
        f.z = h ? u1[4*c1+2] : x1[4*c1+0];
        f.w = h ? u1[4*c1+3] : x1[4*c1+1];
      }
      acc2 = mfma16(f, A2w[kc2], acc2);
    }

    // masks (int4 per 4-row group) + pe[j=c][e-row] reload (L1-resident region)
    float v[16], pe_r[16];
    #pragma unroll
    for (int g = 0; g < 4; ++g) {
      int eb = 8*g + 4*h;
      int4 mm = *(const int4*)(mask + e0 + eb);
      v[4*g+0] = mm.x ? acc2[4*g+0] : NEG_HUGE;
      v[4*g+1] = mm.y ? acc2[4*g+1] : NEG_HUGE;
      v[4*g+2] = mm.z ? acc2[4*g+2] : NEG_HUGE;
      v[4*g+3] = mm.w ? acc2[4*g+3] : NEG_HUGE;
      #pragma unroll
      for (int i = 0; i < 4; ++i)
        pe_r[4*g+i] = (float)*(const _Float16*)(peh_ws + (size_t)(e0 + eb + i)*32 + c);
    }

    float mA = v[0], mB = v[8];
    #pragma unroll
    for (int r = 1; r < 8; ++r) { mA = fmaxf(mA, v[r]); mB = fmaxf(mB, v[r+8]); }
    mA = fmaxf(mA, __shfl_xor(mA, 32));
    mB = fmaxf(mB, __shfl_xor(mB, 32));

    float sA = 0.f, wA = 0.f, sB = 0.f, wB = 0.f;
    #pragma unroll
    for (int r = 0; r < 8; ++r) {
      float pa = __expf(v[r]   - mA);
      float pb = __expf(v[r+8] - mB);
      sA += pa; wA = fmaf(pa, pe_r[r],   wA);
      sB += pb; wB = fmaf(pb, pe_r[r+8], wB);
    }
    sA += __shfl_xor(sA, 32); wA += __shfl_xor(wA, 32);
    sB += __shfl_xor(sB, 32); wB += __shfl_xor(wB, 32);

    float num = h ? wB : wA;
    float den = h ? sB : sA;
    so[c][wv*32 + tt*2 + h] = __fdividef(num, den);
  }

  __syncthreads();
  // full-cache-line writes: thread t covers 64B of one output row
  const int n0 = (blockIdx.x & 255) * 128;
  const int r = threadIdx.x >> 3, uu = threadIdx.x & 7;
  float4* dst = (float4*)(out + (size_t)b*(DIM*NN) + (size_t)r*NN + n0 + uu*16);
  #pragma unroll
  for (int i = 0; i < 4; ++i) dst[i] = *(float4*)&so[r][uu*16 + i*4];
}

extern "C" void kernel_launch(void* const* d_in, const int* in_sizes, int n_in,
                              void* d_out, int out_size, void* d_ws, size_t ws_size,
                              hipStream_t stream) {
  (void)in_sizes; (void)n_in; (void)out_size; (void)ws_size;
  const float* q_xyzs   = (const float*)d_in[0];
  const float* k_xyzs   = (const float*)d_in[1];
  const int*   knn_idx  = (const int*)d_in[2];
  const int*   mask     = (const int*)d_in[3];
  const float* pre_w1   = (const float*)d_in[4];
  const float* pre_b1   = (const float*)d_in[5];
  const float* pre_gn_w = (const float*)d_in[6];
  const float* pre_gn_b = (const float*)d_in[7];
  const float* pre_w2   = (const float*)d_in[8];
  const float* pre_b2   = (const float*)d_in[9];
  const float* attn_w1  = (const float*)d_in[10];
  const float* attn_b1  = (const float*)d_in[11];
  const float* attn_gn_w= (const float*)d_in[12];
  const float* attn_gn_b= (const float*)d_in[13];
  const float* attn_w2  = (const float*)d_in[14];
  const float* attn_b2  = (const float*)d_in[15];
  float* ws  = (float*)d_ws;
  float* out = (float*)d_out;
  unsigned short* peh_ws = (unsigned short*)((char*)d_ws + PE_BYTE_OFF);

  hipMemsetAsync(ws, 0, (64 + 4*1056)*sizeof(float), stream);
  k_packw <<<dim3(1),        64, 0, stream>>>(pre_w2, attn_w2, (unsigned*)ws);
  k_lpmom <<<dim3(NB*256),  256, 0, stream>>>(q_xyzs, k_xyzs, knn_idx, ws);
  k_fold1 <<<dim3(NB),       64, 0, stream>>>(pre_w1, pre_b1, pre_gn_w, pre_gn_b, ws);
  k_pe    <<<dim3(NB*256),  256, 0, stream>>>(q_xyzs, k_xyzs, knn_idx, pre_b2, ws, peh_ws);
  k_pemom <<<dim3(NB*128),  256, 0, stream>>>(peh_ws, ws);
  k_fold2m<<<dim3(NB),       64, 0, stream>>>(attn_w1, attn_b1, attn_gn_w, attn_gn_b, ws);
  k_out   <<<dim3(NB*256),  256, 0, stream>>>(peh_ws, mask, attn_b2, ws, out);
}